// Round 7
// baseline (447.343 us; speedup 1.0000x reference)
//
#include <hip/hip_runtime.h>

#define NUM_USER 60000
#define NUM_ITEM 40000
#define NN 100000
#define NE 500000
#define DIM 64
#define KF 4
#define SCAN_CHUNK 512
#define NBLK_SCAN ((NN + 1 + SCAN_CHUNK - 1) / SCAN_CHUNK)
// padded slot-count upper bounds (each node rounds up to multiple of 4)
#define NEPU_MAX (NE + 3 * NUM_USER)   // 680000 user-side slots max
#define NEPI_MAX (NE + 3 * NUM_ITEM)   // 620000 item-side slots max
#define MAXU_SLOTS 44                  // register-cached user path handles <=44 slots
#define NB_INIT (NN * 64 / 256)        // 25000 blocks: one wave per node
#define NB_COUNT4 ((NE / 4 + 255) / 256)
#define NB_W0 ((NEPU_MAX + 255) / 256)
#define NB_PAD ((NN + 255) / 256)

// sum within each 16-lane group (butterfly: all lanes get result)
__device__ __forceinline__ float red16(float v) {
    v += __shfl_xor(v, 1);
    v += __shfl_xor(v, 2);
    v += __shfl_xor(v, 4);
    v += __shfl_xor(v, 8);
    return v;
}

__device__ __forceinline__ float b2f(unsigned short u) {
    return __uint_as_float(((unsigned)u) << 16);
}
__device__ __forceinline__ unsigned short f2b(float x) {
    unsigned u = __float_as_uint(x);
    u = (u + 0x7fffu + ((u >> 16) & 1u)) >> 16;   // RNE
    return (unsigned short)u;
}
// combined item word: high16 = T (bf16 bits), low16 = ego (bf16 bits)
__device__ __forceinline__ float cvt_lo(unsigned c) { return __uint_as_float(c << 16); }
__device__ __forceinline__ float cvt_hi(unsigned c) { return __uint_as_float(c & 0xffff0000u); }
// pack hi16 halves of two combined words: lo16(out)=hi16(c0), hi16(out)=hi16(c1)
__device__ __forceinline__ unsigned packhi(unsigned c0, unsigned c1) {
#if defined(__has_builtin) && __has_builtin(__builtin_amdgcn_perm)
    return __builtin_amdgcn_perm(c1, c0, 0x07060302u);
#else
    return (c0 >> 16) | (c1 & 0xffff0000u);
#endif
}
// pack lo16 halves: lo16(out)=lo16(c0), hi16(out)=lo16(c1)
__device__ __forceinline__ unsigned packlo(unsigned c0, unsigned c1) {
#if defined(__has_builtin) && __has_builtin(__builtin_amdgcn_perm)
    return __builtin_amdgcn_perm(c1, c0, 0x05040100u);
#else
    return (c0 & 0xffffu) | (c1 << 16);
#endif
}
// mixed-butterfly level: lane keeps the value whose slot-bit matches its lane bit
__device__ __forceinline__ float mixv(float x, float y, bool b, int m) {
    return (b ? y : x) + __shfl_xor(b ? x : y, m);
}

__device__ __forceinline__ float4 softmax4(float4 s) {
    float m = fmaxf(fmaxf(s.x, s.y), fmaxf(s.z, s.w));
    float e0 = __expf(s.x - m), e1 = __expf(s.y - m);
    float e2 = __expf(s.z - m), e3 = __expf(s.w - m);
    float inv = 1.0f / (e0 + e1 + e2 + e3);
    return make_float4(e0 * inv, e1 * inv, e2 * inv, e3 * inv);
}

// iteration-1 update: snew = softmax(S_old)+dot reconstructed as w1*(1/n)+dot.
// Scatters w2 to item-order only (the sole memory consumer); returns w2 so
// iteration 2 runs entirely from registers. Dummy slots: n=0 -> wn=0, no write.
__device__ __forceinline__ float upd1(int jj, int k, float dot, bool wr,
        const float* __restrict__ wuCur, const float2* __restrict__ norm2,
        const int* __restrict__ jit, float* __restrict__ wiW) {
    float w = wuCur[4 * jj + k];
    float2 nn = norm2[jj];
    float snew = fmaf(w, nn.y, dot);
    float m2 = fmaxf(snew, __shfl_xor(snew, 16));
    m2 = fmaxf(m2, __shfl_xor(m2, 32));
    float e = __expf(snew - m2);
    float s2 = e + __shfl_xor(e, 16);
    s2 += __shfl_xor(s2, 32);
    float wn = 0.0f;
    if (nn.x > 0.0f) {
        wn = nn.x * e * (1.0f / s2);
        if (wr) wiW[4 * jit[jj] + k] = wn;
    }
    return wn;
}

// iteration-2 update: snew2 = w2*(1/n)+dot2 with w2 from REGISTER.
// last: write final S; else: w3 = n*softmax(snew2) -> user order only.
__device__ __forceinline__ void upd2(int jj, int k, float wreg, float dot, bool wr,
        const float2* __restrict__ norm2, float* __restrict__ S4f,
        float* __restrict__ wuN, int last) {
    float2 nn = norm2[jj];
    float snew = fmaf(wreg, nn.y, dot);
    if (last) {
        if (wr) S4f[4 * jj + k] = snew;
        return;
    }
    float m2 = fmaxf(snew, __shfl_xor(snew, 16));
    m2 = fmaxf(m2, __shfl_xor(m2, 32));
    float e = __expf(snew - m2);
    float s2 = e + __shfl_xor(e, 16);
    s2 += __shfl_xor(s2, 32);
    if (wr && nn.x > 0.0f) wuN[4 * jj + k] = nn.x * e * (1.0f / s2);
}

// merged: blocks [0, NB_INIT) = per-node init; rest = 4-edge int4 degree count.
__global__ void k_setup(const float* __restrict__ user, const float* __restrict__ item,
                        unsigned short* __restrict__ egoU, unsigned* __restrict__ cmbI,
                        float* __restrict__ allemb, const int* __restrict__ row0,
                        const int* __restrict__ col0, int* __restrict__ cnt) {
    int b = blockIdx.x;
    if (b < NB_INIT) {
        int node = (b * 256 + threadIdx.x) >> 6;   // < NN by construction
        int lane = threadIdx.x & 63;
        int i = node * DIM + lane;
        if (node < NUM_USER) {
            float v = user[i];
            egoU[i] = f2b(v);
            allemb[i] = v;
        } else {
            float v = item[i - NUM_USER * DIM];
            allemb[i] = v;
            float ss = red16(v * v);
            float t = tanhf(v / fmaxf(sqrtf(ss), 1e-12f));
            cmbI[i - NUM_USER * DIM] = (((unsigned)f2b(t)) << 16) | (unsigned)f2b(v);
        }
    } else {
        int t = (b - NB_INIT) * 256 + threadIdx.x;
        if (t >= NE / 4) return;
        int4 r = ((const int4*)row0)[t];
        int4 c = ((const int4*)col0)[t];
        atomicAdd(&cnt[r.x], 1);
        atomicAdd(&cnt[r.y], 1);
        atomicAdd(&cnt[r.z], 1);
        atomicAdd(&cnt[r.w], 1);
        atomicAdd(&cnt[c.x], 1);
        atomicAdd(&cnt[c.y], 1);
        atomicAdd(&cnt[c.z], 1);
        atomicAdd(&cnt[c.w], 1);
    }
}

// --- 3-stage exclusive scan over padded counts -> ptr[NN+1]; dinv fused ---
__global__ void k_scan1(const int* __restrict__ cnt, float* __restrict__ dinv,
                        int* __restrict__ ptr, int* __restrict__ bsum) {
    __shared__ int sm[SCAN_CHUNK];
    int tid = threadIdx.x;
    int idx = blockIdx.x * SCAN_CHUNK + tid;
    int d = (idx < NN) ? cnt[idx] : 0;
    if (idx < NN) dinv[idx] = (d > 0) ? rsqrtf((float)d) : 0.0f;
    int x = (d + 3) & ~3;
    sm[tid] = x;
    __syncthreads();
    for (int off = 1; off < SCAN_CHUNK; off <<= 1) {
        int v = (tid >= off) ? sm[tid - off] : 0;
        __syncthreads();
        sm[tid] += v;
        __syncthreads();
    }
    if (idx <= NN) ptr[idx] = sm[tid] - x;
    if (tid == SCAN_CHUNK - 1) bsum[blockIdx.x] = sm[tid];
}

__global__ void k_scan2(int* __restrict__ bsum, int* __restrict__ offs) {
    __shared__ int sm[256];
    int tid = threadIdx.x;
    int x = (tid < NBLK_SCAN) ? bsum[tid] : 0;
    sm[tid] = x;
    __syncthreads();
    for (int off = 1; off < 256; off <<= 1) {
        int v = (tid >= off) ? sm[tid - off] : 0;
        __syncthreads();
        sm[tid] += v;
        __syncthreads();
    }
    if (tid < NBLK_SCAN) offs[tid] = sm[tid] - x;
}

__global__ void k_scan3(int* __restrict__ ptr, const int* __restrict__ offs,
                        int* __restrict__ pos) {
    int idx = blockIdx.x * blockDim.x + threadIdx.x;
    if (idx > NN) return;
    int v = ptr[idx] + offs[idx / SCAN_CHUNK];
    ptr[idx] = v;
    pos[idx] = v;
}

// fill CSR. user-side slots [0, ptr[NUM_USER]); src ITEM-LOCAL pre-scaled <<6.
// jit[user_slot] = item-local slot of same edge; einv[user_slot] = edge id.
__global__ void k_fill(const int* __restrict__ row0, const int* __restrict__ col0,
                       int* __restrict__ pos, const int* __restrict__ ptr,
                       int* __restrict__ srcadj, int* __restrict__ jit,
                       int* __restrict__ jpos1, int* __restrict__ einv) {
    int e = blockIdx.x * blockDim.x + threadIdx.x;
    if (e >= NE) return;
    int r = row0[e], c = col0[e];
    int ptrU = ptr[NUM_USER];
    int j1 = atomicAdd(&pos[r], 1);
    srcadj[j1] = (c - NUM_USER) << 6;
    jpos1[e] = j1;
    einv[j1] = e;
    int j0 = atomicAdd(&pos[c], 1);
    srcadj[j0] = r << 6;
    jit[j1] = j0 - ptrU;
}

// merged: blocks [0, NB_W0) = slot-parallel weight init (norm {n,1/n} + w1,
// USER order only -- items never consume w1); rest = dummy-slot srcadj=0.
__global__ void k_w0pad(const float* __restrict__ Sin, const int* __restrict__ row0,
                        const int* __restrict__ col0, const int* __restrict__ einv,
                        const float* __restrict__ dinv, const int* __restrict__ ptr,
                        const int* __restrict__ cnt, int* __restrict__ srcadj,
                        float2* __restrict__ norm2, float4* __restrict__ wuA) {
    int b = blockIdx.x;
    if (b < NB_W0) {
        int j = b * 256 + threadIdx.x;
        if (j >= ptr[NUM_USER]) return;
        int e = einv[j];
        if (e < 0) return;   // dummy: stays zero
        float n = dinv[row0[e]] * dinv[col0[e]];
        float4 s = make_float4(Sin[e], Sin[NE + e], Sin[2 * NE + e], Sin[3 * NE + e]);
        float4 p = softmax4(s);
        norm2[j] = make_float2(n, 1.0f / n);
        wuA[j] = make_float4(n * p.x, n * p.y, n * p.z, n * p.w);
    } else {
        int n = (b - NB_W0) * 256 + threadIdx.x;
        if (n >= NN) return;
        int realend = ptr[n] + cnt[n];
        int end = ptr[n + 1];
        for (int j = realend; j < end; ++j) srcadj[j] = 0;
    }
}

// Scur4 (slot order, written by last user kernel) -> Sout [4][E] edge order
__global__ void k_sout(const float4* __restrict__ Scur4, const int* __restrict__ jpos1,
                       float* __restrict__ Sout) {
    int e = blockIdx.x * blockDim.x + threadIdx.x;
    if (e >= NE) return;
    float4 s = Scur4[jpos1[e]];
    Sout[e] = s.x;
    Sout[NE + e] = s.y;
    Sout[2 * NE + e] = s.z;
    Sout[3 * NE + e] = s.w;
}

// ---- user conv-1 macros: gather + FMA + cache T (tp) AND ego (ep) packed ----
#define UCONV16(JOFF, TP0) do { \
    int j = beg + (JOFF); \
    int4 sA = *(const int4*)(srcadj + j); \
    int4 sB = *(const int4*)(srcadj + j + 4); \
    int4 sC = *(const int4*)(srcadj + j + 8); \
    int4 sD = *(const int4*)(srcadj + j + 12); \
    unsigned c0 = cmbI[sA.x + lane]; \
    unsigned c1 = cmbI[sA.y + lane]; \
    unsigned c2 = cmbI[sA.z + lane]; \
    unsigned c3 = cmbI[sA.w + lane]; \
    unsigned c4 = cmbI[sB.x + lane]; \
    unsigned c5 = cmbI[sB.y + lane]; \
    unsigned c6 = cmbI[sB.z + lane]; \
    unsigned c7 = cmbI[sB.w + lane]; \
    unsigned c8 = cmbI[sC.x + lane]; \
    unsigned c9 = cmbI[sC.y + lane]; \
    unsigned c10 = cmbI[sC.z + lane]; \
    unsigned c11 = cmbI[sC.w + lane]; \
    unsigned c12 = cmbI[sD.x + lane]; \
    unsigned c13 = cmbI[sD.y + lane]; \
    unsigned c14 = cmbI[sD.z + lane]; \
    unsigned c15 = cmbI[sD.w + lane]; \
    a0 = fmaf(wuCur[4 * j + k], cvt_lo(c0), a0); \
    a1 = fmaf(wuCur[4 * j + 4 + k], cvt_lo(c1), a1); \
    a2 = fmaf(wuCur[4 * j + 8 + k], cvt_lo(c2), a2); \
    a3 = fmaf(wuCur[4 * j + 12 + k], cvt_lo(c3), a3); \
    a0 = fmaf(wuCur[4 * j + 16 + k], cvt_lo(c4), a0); \
    a1 = fmaf(wuCur[4 * j + 20 + k], cvt_lo(c5), a1); \
    a2 = fmaf(wuCur[4 * j + 24 + k], cvt_lo(c6), a2); \
    a3 = fmaf(wuCur[4 * j + 28 + k], cvt_lo(c7), a3); \
    a0 = fmaf(wuCur[4 * j + 32 + k], cvt_lo(c8), a0); \
    a1 = fmaf(wuCur[4 * j + 36 + k], cvt_lo(c9), a1); \
    a2 = fmaf(wuCur[4 * j + 40 + k], cvt_lo(c10), a2); \
    a3 = fmaf(wuCur[4 * j + 44 + k], cvt_lo(c11), a3); \
    a0 = fmaf(wuCur[4 * j + 48 + k], cvt_lo(c12), a0); \
    a1 = fmaf(wuCur[4 * j + 52 + k], cvt_lo(c13), a1); \
    a2 = fmaf(wuCur[4 * j + 56 + k], cvt_lo(c14), a2); \
    a3 = fmaf(wuCur[4 * j + 60 + k], cvt_lo(c15), a3); \
    tp[(TP0) + 0] = packhi(c0, c1);  ep[(TP0) + 0] = packlo(c0, c1); \
    tp[(TP0) + 1] = packhi(c2, c3);  ep[(TP0) + 1] = packlo(c2, c3); \
    tp[(TP0) + 2] = packhi(c4, c5);  ep[(TP0) + 2] = packlo(c4, c5); \
    tp[(TP0) + 3] = packhi(c6, c7);  ep[(TP0) + 3] = packlo(c6, c7); \
    tp[(TP0) + 4] = packhi(c8, c9);  ep[(TP0) + 4] = packlo(c8, c9); \
    tp[(TP0) + 5] = packhi(c10, c11); ep[(TP0) + 5] = packlo(c10, c11); \
    tp[(TP0) + 6] = packhi(c12, c13); ep[(TP0) + 6] = packlo(c12, c13); \
    tp[(TP0) + 7] = packhi(c14, c15); ep[(TP0) + 7] = packlo(c14, c15); \
} while (0)

#define UCONV8(JOFF, TP0) do { \
    int j = beg + (JOFF); \
    int4 sA = *(const int4*)(srcadj + j); \
    int4 sB = *(const int4*)(srcadj + j + 4); \
    unsigned c0 = cmbI[sA.x + lane]; \
    unsigned c1 = cmbI[sA.y + lane]; \
    unsigned c2 = cmbI[sA.z + lane]; \
    unsigned c3 = cmbI[sA.w + lane]; \
    unsigned c4 = cmbI[sB.x + lane]; \
    unsigned c5 = cmbI[sB.y + lane]; \
    unsigned c6 = cmbI[sB.z + lane]; \
    unsigned c7 = cmbI[sB.w + lane]; \
    a0 = fmaf(wuCur[4 * j + k], cvt_lo(c0), a0); \
    a1 = fmaf(wuCur[4 * j + 4 + k], cvt_lo(c1), a1); \
    a2 = fmaf(wuCur[4 * j + 8 + k], cvt_lo(c2), a2); \
    a3 = fmaf(wuCur[4 * j + 12 + k], cvt_lo(c3), a3); \
    a0 = fmaf(wuCur[4 * j + 16 + k], cvt_lo(c4), a0); \
    a1 = fmaf(wuCur[4 * j + 20 + k], cvt_lo(c5), a1); \
    a2 = fmaf(wuCur[4 * j + 24 + k], cvt_lo(c6), a2); \
    a3 = fmaf(wuCur[4 * j + 28 + k], cvt_lo(c7), a3); \
    tp[(TP0) + 0] = packhi(c0, c1);  ep[(TP0) + 0] = packlo(c0, c1); \
    tp[(TP0) + 1] = packhi(c2, c3);  ep[(TP0) + 1] = packlo(c2, c3); \
    tp[(TP0) + 2] = packhi(c4, c5);  ep[(TP0) + 2] = packlo(c4, c5); \
    tp[(TP0) + 3] = packhi(c6, c7);  ep[(TP0) + 3] = packlo(c6, c7); \
} while (0)

#define UCONV4(JOFF, TP0) do { \
    int j = beg + (JOFF); \
    int4 sA = *(const int4*)(srcadj + j); \
    unsigned c0 = cmbI[sA.x + lane]; \
    unsigned c1 = cmbI[sA.y + lane]; \
    unsigned c2 = cmbI[sA.z + lane]; \
    unsigned c3 = cmbI[sA.w + lane]; \
    a0 = fmaf(wuCur[4 * j + k], cvt_lo(c0), a0); \
    a1 = fmaf(wuCur[4 * j + 4 + k], cvt_lo(c1), a1); \
    a2 = fmaf(wuCur[4 * j + 8 + k], cvt_lo(c2), a2); \
    a3 = fmaf(wuCur[4 * j + 12 + k], cvt_lo(c3), a3); \
    tp[(TP0) + 0] = packhi(c0, c1);  ep[(TP0) + 0] = packlo(c0, c1); \
    tp[(TP0) + 1] = packhi(c2, c3);  ep[(TP0) + 1] = packlo(c2, c3); \
} while (0)

// ---- score butterflies from the register T cache; DOT = dot for this
// lane's slot (16-blk: lane&15, 8-blk: lane&7 dup x2, 4-blk: lane&3 dup x4)
#define SCORE16(TP0, U, DOT) do { \
    float p0 = (U) * __uint_as_float(tp[(TP0) + 0] << 16); \
    float p1 = (U) * __uint_as_float(tp[(TP0) + 0] & 0xffff0000u); \
    float p2 = (U) * __uint_as_float(tp[(TP0) + 1] << 16); \
    float p3 = (U) * __uint_as_float(tp[(TP0) + 1] & 0xffff0000u); \
    float p4 = (U) * __uint_as_float(tp[(TP0) + 2] << 16); \
    float p5 = (U) * __uint_as_float(tp[(TP0) + 2] & 0xffff0000u); \
    float p6 = (U) * __uint_as_float(tp[(TP0) + 3] << 16); \
    float p7 = (U) * __uint_as_float(tp[(TP0) + 3] & 0xffff0000u); \
    float p8 = (U) * __uint_as_float(tp[(TP0) + 4] << 16); \
    float p9 = (U) * __uint_as_float(tp[(TP0) + 4] & 0xffff0000u); \
    float p10 = (U) * __uint_as_float(tp[(TP0) + 5] << 16); \
    float p11 = (U) * __uint_as_float(tp[(TP0) + 5] & 0xffff0000u); \
    float p12 = (U) * __uint_as_float(tp[(TP0) + 6] << 16); \
    float p13 = (U) * __uint_as_float(tp[(TP0) + 6] & 0xffff0000u); \
    float p14 = (U) * __uint_as_float(tp[(TP0) + 7] << 16); \
    float p15 = (U) * __uint_as_float(tp[(TP0) + 7] & 0xffff0000u); \
    float q0 = mixv(p0, p1, b0, 1); \
    float q1 = mixv(p2, p3, b0, 1); \
    float q2 = mixv(p4, p5, b0, 1); \
    float q3 = mixv(p6, p7, b0, 1); \
    float q4 = mixv(p8, p9, b0, 1); \
    float q5 = mixv(p10, p11, b0, 1); \
    float q6 = mixv(p12, p13, b0, 1); \
    float q7 = mixv(p14, p15, b0, 1); \
    float r0 = mixv(q0, q1, b1, 2); \
    float r1 = mixv(q2, q3, b1, 2); \
    float r2 = mixv(q4, q5, b1, 2); \
    float r3 = mixv(q6, q7, b1, 2); \
    float s0_ = mixv(r0, r1, b2, 4); \
    float s1_ = mixv(r2, r3, b2, 4); \
    DOT = mixv(s0_, s1_, b3, 8); \
} while (0)

#define SCORE8(TP0, U, DOT) do { \
    float p0 = (U) * __uint_as_float(tp[(TP0) + 0] << 16); \
    float p1 = (U) * __uint_as_float(tp[(TP0) + 0] & 0xffff0000u); \
    float p2 = (U) * __uint_as_float(tp[(TP0) + 1] << 16); \
    float p3 = (U) * __uint_as_float(tp[(TP0) + 1] & 0xffff0000u); \
    float p4 = (U) * __uint_as_float(tp[(TP0) + 2] << 16); \
    float p5 = (U) * __uint_as_float(tp[(TP0) + 2] & 0xffff0000u); \
    float p6 = (U) * __uint_as_float(tp[(TP0) + 3] << 16); \
    float p7 = (U) * __uint_as_float(tp[(TP0) + 3] & 0xffff0000u); \
    float q0 = mixv(p0, p1, b0, 1); \
    float q1 = mixv(p2, p3, b0, 1); \
    float q2 = mixv(p4, p5, b0, 1); \
    float q3 = mixv(p6, p7, b0, 1); \
    float r0 = mixv(q0, q1, b1, 2); \
    float r1 = mixv(q2, q3, b1, 2); \
    float t_ = mixv(r0, r1, b2, 4); \
    t_ += __shfl_xor(t_, 8); \
    DOT = t_; \
} while (0)

#define SCORE4(TP0, U, DOT) do { \
    float p0 = (U) * __uint_as_float(tp[(TP0) + 0] << 16); \
    float p1 = (U) * __uint_as_float(tp[(TP0) + 0] & 0xffff0000u); \
    float p2 = (U) * __uint_as_float(tp[(TP0) + 1] << 16); \
    float p3 = (U) * __uint_as_float(tp[(TP0) + 1] & 0xffff0000u); \
    float q0 = mixv(p0, p1, b0, 1); \
    float q1 = mixv(p2, p3, b0, 1); \
    float r0 = mixv(q0, q1, b1, 2); \
    r0 += __shfl_xor(r0, 4); \
    r0 += __shfl_xor(r0, 8); \
    DOT = r0; \
} while (0)

// ---- conv-2 from registers: weights via shfl from the upd1 result layout
// (lane 16k+s holds w2 for slot s, factor k), ego from packed ep cache.
#define CONV2_16(W, EP0) do { \
    int g = lane & 48; \
    unsigned e0 = ep[(EP0) + 0], e1 = ep[(EP0) + 1]; \
    unsigned e2_ = ep[(EP0) + 2], e3_ = ep[(EP0) + 3]; \
    unsigned e4 = ep[(EP0) + 4], e5 = ep[(EP0) + 5]; \
    unsigned e6 = ep[(EP0) + 6], e7 = ep[(EP0) + 7]; \
    a0 = fmaf(__shfl((W), g | 0), cvt_lo(e0), a0); \
    a1 = fmaf(__shfl((W), g | 1), cvt_hi(e0), a1); \
    a2 = fmaf(__shfl((W), g | 2), cvt_lo(e1), a2); \
    a3 = fmaf(__shfl((W), g | 3), cvt_hi(e1), a3); \
    a0 = fmaf(__shfl((W), g | 4), cvt_lo(e2_), a0); \
    a1 = fmaf(__shfl((W), g | 5), cvt_hi(e2_), a1); \
    a2 = fmaf(__shfl((W), g | 6), cvt_lo(e3_), a2); \
    a3 = fmaf(__shfl((W), g | 7), cvt_hi(e3_), a3); \
    a0 = fmaf(__shfl((W), g | 8), cvt_lo(e4), a0); \
    a1 = fmaf(__shfl((W), g | 9), cvt_hi(e4), a1); \
    a2 = fmaf(__shfl((W), g | 10), cvt_lo(e5), a2); \
    a3 = fmaf(__shfl((W), g | 11), cvt_hi(e5), a3); \
    a0 = fmaf(__shfl((W), g | 12), cvt_lo(e6), a0); \
    a1 = fmaf(__shfl((W), g | 13), cvt_hi(e6), a1); \
    a2 = fmaf(__shfl((W), g | 14), cvt_lo(e7), a2); \
    a3 = fmaf(__shfl((W), g | 15), cvt_hi(e7), a3); \
} while (0)

#define CONV2_8(W, EP0) do { \
    int g = lane & 48; \
    unsigned e0 = ep[(EP0) + 0], e1 = ep[(EP0) + 1]; \
    unsigned e2_ = ep[(EP0) + 2], e3_ = ep[(EP0) + 3]; \
    a0 = fmaf(__shfl((W), g | 0), cvt_lo(e0), a0); \
    a1 = fmaf(__shfl((W), g | 1), cvt_hi(e0), a1); \
    a2 = fmaf(__shfl((W), g | 2), cvt_lo(e1), a2); \
    a3 = fmaf(__shfl((W), g | 3), cvt_hi(e1), a3); \
    a0 = fmaf(__shfl((W), g | 4), cvt_lo(e2_), a0); \
    a1 = fmaf(__shfl((W), g | 5), cvt_hi(e2_), a1); \
    a2 = fmaf(__shfl((W), g | 6), cvt_lo(e3_), a2); \
    a3 = fmaf(__shfl((W), g | 7), cvt_hi(e3_), a3); \
} while (0)

#define CONV2_4(W, EP0) do { \
    int g = lane & 48; \
    unsigned e0 = ep[(EP0) + 0], e1 = ep[(EP0) + 1]; \
    a0 = fmaf(__shfl((W), g | 0), cvt_lo(e0), a0); \
    a1 = fmaf(__shfl((W), g | 1), cvt_hi(e0), a1); \
    a2 = fmaf(__shfl((W), g | 2), cvt_lo(e1), a2); \
    a3 = fmaf(__shfl((W), g | 3), cvt_hi(e1), a3); \
} while (0)

// Fused full-layer user kernel: conv1 (gather, caches T+ego) -> score1 ->
// w2 (registers + item-order scatter) -> conv2 (pure register) -> score2 ->
// w3 (user order) or final S. One cmbI gather sweep per LAYER instead of two.
__global__ __launch_bounds__(256, 4) void k_user_layer(
        const int* __restrict__ ptr, const int* __restrict__ srcadj,
        const float* __restrict__ wuCur, const float2* __restrict__ norm2,
        const int* __restrict__ jit, float* __restrict__ wiW,
        float* __restrict__ wuN, float* __restrict__ wsc,
        float* __restrict__ S4f, const unsigned* __restrict__ cmbI,
        unsigned short* __restrict__ xnextU, float* __restrict__ allemb,
        int writeEgo, int last) {
    int node = (blockIdx.x * blockDim.x + threadIdx.x) >> 6;
    int lane = threadIdx.x & 63;
    if (node >= NUM_USER) return;
    int beg = __builtin_amdgcn_readfirstlane(ptr[node]);
    int end = __builtin_amdgcn_readfirstlane(ptr[node + 1]);
    int count = end - beg;
    int k = lane >> 4;
    bool b0 = lane & 1, b1 = lane & 2, b2 = lane & 4, b3 = lane & 8;

    float a0 = 0.0f, a1 = 0.0f, a2 = 0.0f, a3 = 0.0f;

    if (count > MAXU_SLOTS) {
        // ---- big-node fallback: two memory passes, w2 via wsc scratch ----
        for (int j = beg; j < end; j += 4) {
            int4 s = *(const int4*)(srcadj + j);
            a0 = fmaf(wuCur[4 * j + k], cvt_lo(cmbI[s.x + lane]), a0);
            a1 = fmaf(wuCur[4 * j + 4 + k], cvt_lo(cmbI[s.y + lane]), a1);
            a2 = fmaf(wuCur[4 * j + 8 + k], cvt_lo(cmbI[s.z + lane]), a2);
            a3 = fmaf(wuCur[4 * j + 12 + k], cvt_lo(cmbI[s.w + lane]), a3);
        }
        float acc = (a0 + a1) + (a2 + a3);
        float u = acc / fmaxf(sqrtf(red16(acc * acc)), 1e-12f);
        for (int j = beg; j < end; j += 4) {
            int4 s = *(const int4*)(srcadj + j);
            float p0 = red16(u * cvt_hi(cmbI[s.x + lane]));
            float p1 = red16(u * cvt_hi(cmbI[s.y + lane]));
            float p2 = red16(u * cvt_hi(cmbI[s.z + lane]));
            float p3 = red16(u * cvt_hi(cmbI[s.w + lane]));
            int sl = lane & 3;
            float dv = p0;
            dv = (sl == 1) ? p1 : dv;
            dv = (sl == 2) ? p2 : dv;
            dv = (sl == 3) ? p3 : dv;
            int jj = j + sl;
            float w = wuCur[4 * jj + k];
            float2 nn = norm2[jj];
            float snew = fmaf(w, nn.y, dv);
            float m2 = fmaxf(snew, __shfl_xor(snew, 16));
            m2 = fmaxf(m2, __shfl_xor(m2, 32));
            float e = __expf(snew - m2);
            float s2 = e + __shfl_xor(e, 16);
            s2 += __shfl_xor(s2, 32);
            if (!(lane & 12) && nn.x > 0.0f) {
                float wn = nn.x * e * (1.0f / s2);
                wsc[4 * jj + k] = wn;
                wiW[4 * jit[jj] + k] = wn;
            }
        }
        a0 = a1 = a2 = a3 = 0.0f;
        for (int j = beg; j < end; j += 4) {
            int4 s = *(const int4*)(srcadj + j);
            a0 = fmaf(wsc[4 * j + k], cvt_lo(cmbI[s.x + lane]), a0);
            a1 = fmaf(wsc[4 * j + 4 + k], cvt_lo(cmbI[s.y + lane]), a1);
            a2 = fmaf(wsc[4 * j + 8 + k], cvt_lo(cmbI[s.z + lane]), a2);
            a3 = fmaf(wsc[4 * j + 12 + k], cvt_lo(cmbI[s.w + lane]), a3);
        }
        float acc2 = (a0 + a1) + (a2 + a3);
        int i = node * DIM + lane;
        allemb[i] += acc2;
        if (writeEgo) xnextU[i] = f2b(acc2);
        float u2 = acc2 / fmaxf(sqrtf(red16(acc2 * acc2)), 1e-12f);
        for (int j = beg; j < end; j += 4) {
            int4 s = *(const int4*)(srcadj + j);
            float p0 = red16(u2 * cvt_hi(cmbI[s.x + lane]));
            float p1 = red16(u2 * cvt_hi(cmbI[s.y + lane]));
            float p2 = red16(u2 * cvt_hi(cmbI[s.z + lane]));
            float p3 = red16(u2 * cvt_hi(cmbI[s.w + lane]));
            int sl = lane & 3;
            float dv = p0;
            dv = (sl == 1) ? p1 : dv;
            dv = (sl == 2) ? p2 : dv;
            dv = (sl == 3) ? p3 : dv;
            int jj = j + sl;
            float w2v = wsc[4 * jj + k];
            float2 nn = norm2[jj];
            float snew = fmaf(w2v, nn.y, dv);
            if (last) {
                if (!(lane & 12)) S4f[4 * jj + k] = snew;
            } else {
                float m2 = fmaxf(snew, __shfl_xor(snew, 16));
                m2 = fmaxf(m2, __shfl_xor(m2, 32));
                float e = __expf(snew - m2);
                float s2 = e + __shfl_xor(e, 16);
                s2 += __shfl_xor(s2, 32);
                if (!(lane & 12) && nn.x > 0.0f)
                    wuN[4 * jj + k] = nn.x * e * (1.0f / s2);
            }
        }
        return;
    }

    // ---- register-cached path ----
    unsigned tp[22];   // T packed 2 slots/word
    unsigned ep[22];   // ego packed 2 slots/word
    int rem = count & 15;
    int rbase = count & ~15;

    if (count >= 16) UCONV16(0, 0);
    if (count >= 32) UCONV16(16, 8);
    if (rem & 8) UCONV8(rbase, 16);
    if (rem & 4) UCONV4(rbase + (rem & 8), 20);

    float acc = (a0 + a1) + (a2 + a3);
    float u = acc / fmaxf(sqrtf(red16(acc * acc)), 1e-12f);

    // score1 + update1: w2 into registers (+ item-order scatter)
    float w16a = 0.0f, w16b = 0.0f, w8t = 0.0f, w4t = 0.0f;
    if (count >= 16) {
        float d;
        SCORE16(0, u, d);
        w16a = upd1(beg + (lane & 15), k, d, true, wuCur, norm2, jit, wiW);
    }
    if (count >= 32) {
        float d;
        SCORE16(8, u, d);
        w16b = upd1(beg + 16 + (lane & 15), k, d, true, wuCur, norm2, jit, wiW);
    }
    if (rem & 8) {
        float d;
        SCORE8(16, u, d);
        w8t = upd1(beg + rbase + (lane & 7), k, d, !(lane & 8), wuCur, norm2, jit, wiW);
    }
    if (rem & 4) {
        float d;
        SCORE4(20, u, d);
        w4t = upd1(beg + rbase + (rem & 8) + (lane & 3), k, d, !(lane & 12),
                   wuCur, norm2, jit, wiW);
    }

    // conv2: pure register math (shfl weights + packed ego cache)
    a0 = a1 = a2 = a3 = 0.0f;
    if (count >= 16) CONV2_16(w16a, 0);
    if (count >= 32) CONV2_16(w16b, 8);
    if (rem & 8) CONV2_8(w8t, 16);
    if (rem & 4) CONV2_4(w4t, 20);
    float acc2 = (a0 + a1) + (a2 + a3);

    int i = node * DIM + lane;
    allemb[i] += acc2;
    if (writeEgo) xnextU[i] = f2b(acc2);

    float u2 = acc2 / fmaxf(sqrtf(red16(acc2 * acc2)), 1e-12f);

    // score2 + update2: softmax(S1) reconstructed from register w2
    if (count >= 16) {
        float d;
        SCORE16(0, u2, d);
        upd2(beg + (lane & 15), k, w16a, d, true, norm2, S4f, wuN, last);
    }
    if (count >= 32) {
        float d;
        SCORE16(8, u2, d);
        upd2(beg + 16 + (lane & 15), k, w16b, d, true, norm2, S4f, wuN, last);
    }
    if (rem & 8) {
        float d;
        SCORE8(16, u2, d);
        upd2(beg + rbase + (lane & 7), k, w8t, d, !(lane & 8), norm2, S4f, wuN, last);
    }
    if (rem & 4) {
        float d;
        SCORE4(20, u2, d);
        upd2(beg + rbase + (rem & 8) + (lane & 3), k, w4t, d, !(lane & 12),
             norm2, S4f, wuN, last);
    }
}

// item-side conv (layer end only): 16-deep gather of egoU rows with wi weights
__global__ __launch_bounds__(256) void k_item_layer(
        const int* __restrict__ ptr, const int* __restrict__ srcadj,
        const float* __restrict__ wiCur, const unsigned short* __restrict__ egoU,
        unsigned* __restrict__ cmbNext, float* __restrict__ allemb, int writeT) {
    int idx = (blockIdx.x * blockDim.x + threadIdx.x) >> 6;
    int lane = threadIdx.x & 63;
    if (idx >= NUM_ITEM) return;
    int node = NUM_USER + idx;
    int beg = __builtin_amdgcn_readfirstlane(ptr[node]);
    int end = __builtin_amdgcn_readfirstlane(ptr[node + 1]);
    int count = end - beg;
    int ptrU = __builtin_amdgcn_readfirstlane(ptr[NUM_USER]);
    int k = lane >> 4;
    const float* wT = wiCur + (size_t)4 * (beg - ptrU);

    float a0 = 0.0f, a1 = 0.0f, a2 = 0.0f, a3 = 0.0f;
    int t = 0;
    for (; t + 16 <= count; t += 16) {
        int4 sA = *(const int4*)(srcadj + beg + t);
        int4 sB = *(const int4*)(srcadj + beg + t + 4);
        int4 sC = *(const int4*)(srcadj + beg + t + 8);
        int4 sD = *(const int4*)(srcadj + beg + t + 12);
        a0 = fmaf(wT[4 * t + k], b2f(egoU[sA.x + lane]), a0);
        a1 = fmaf(wT[4 * t + 4 + k], b2f(egoU[sA.y + lane]), a1);
        a2 = fmaf(wT[4 * t + 8 + k], b2f(egoU[sA.z + lane]), a2);
        a3 = fmaf(wT[4 * t + 12 + k], b2f(egoU[sA.w + lane]), a3);
        a0 = fmaf(wT[4 * t + 16 + k], b2f(egoU[sB.x + lane]), a0);
        a1 = fmaf(wT[4 * t + 20 + k], b2f(egoU[sB.y + lane]), a1);
        a2 = fmaf(wT[4 * t + 24 + k], b2f(egoU[sB.z + lane]), a2);
        a3 = fmaf(wT[4 * t + 28 + k], b2f(egoU[sB.w + lane]), a3);
        a0 = fmaf(wT[4 * t + 32 + k], b2f(egoU[sC.x + lane]), a0);
        a1 = fmaf(wT[4 * t + 36 + k], b2f(egoU[sC.y + lane]), a1);
        a2 = fmaf(wT[4 * t + 40 + k], b2f(egoU[sC.z + lane]), a2);
        a3 = fmaf(wT[4 * t + 44 + k], b2f(egoU[sC.w + lane]), a3);
        a0 = fmaf(wT[4 * t + 48 + k], b2f(egoU[sD.x + lane]), a0);
        a1 = fmaf(wT[4 * t + 52 + k], b2f(egoU[sD.y + lane]), a1);
        a2 = fmaf(wT[4 * t + 56 + k], b2f(egoU[sD.z + lane]), a2);
        a3 = fmaf(wT[4 * t + 60 + k], b2f(egoU[sD.w + lane]), a3);
    }
    if (count & 8) {
        int4 sA = *(const int4*)(srcadj + beg + t);
        int4 sB = *(const int4*)(srcadj + beg + t + 4);
        a0 = fmaf(wT[4 * t + k], b2f(egoU[sA.x + lane]), a0);
        a1 = fmaf(wT[4 * t + 4 + k], b2f(egoU[sA.y + lane]), a1);
        a2 = fmaf(wT[4 * t + 8 + k], b2f(egoU[sA.z + lane]), a2);
        a3 = fmaf(wT[4 * t + 12 + k], b2f(egoU[sA.w + lane]), a3);
        a0 = fmaf(wT[4 * t + 16 + k], b2f(egoU[sB.x + lane]), a0);
        a1 = fmaf(wT[4 * t + 20 + k], b2f(egoU[sB.y + lane]), a1);
        a2 = fmaf(wT[4 * t + 24 + k], b2f(egoU[sB.z + lane]), a2);
        a3 = fmaf(wT[4 * t + 28 + k], b2f(egoU[sB.w + lane]), a3);
        t += 8;
    }
    if (count & 4) {
        int4 sA = *(const int4*)(srcadj + beg + t);
        a0 = fmaf(wT[4 * t + k], b2f(egoU[sA.x + lane]), a0);
        a1 = fmaf(wT[4 * t + 4 + k], b2f(egoU[sA.y + lane]), a1);
        a2 = fmaf(wT[4 * t + 8 + k], b2f(egoU[sA.z + lane]), a2);
        a3 = fmaf(wT[4 * t + 12 + k], b2f(egoU[sA.w + lane]), a3);
    }
    float acc = (a0 + a1) + (a2 + a3);
    int i = node * DIM + lane;
    allemb[i] += acc;
    if (writeT) {
        float ss = red16(acc * acc);
        float tt = tanhf(acc / fmaxf(sqrtf(ss), 1e-12f));
        cmbNext[idx * DIM + lane] = (((unsigned)f2b(tt)) << 16) | (unsigned)f2b(acc);
    }
}

extern "C" void kernel_launch(void* const* d_in, const int* in_sizes, int n_in,
                              void* d_out, int out_size, void* d_ws, size_t ws_size,
                              hipStream_t stream) {
    const float* user = (const float*)d_in[0];
    const float* item = (const float*)d_in[1];
    const float* S_in = (const float*)d_in[2];
    const int* edge = (const int*)d_in[3];
    const int* row0 = edge;
    const int* col0 = edge + NE;

    float* out = (float*)d_out;
    float* allemb = out;              // NN*DIM floats
    float* Sfinal = out + NN * DIM;   // KF*NE floats

    char* ws = (char*)d_ws;
    size_t off = 0;
    auto carve = [&](size_t bytes) { void* p = ws + off; off += (bytes + 255) & ~(size_t)255; return p; };
    int* cnt = (int*)carve((NN + 1) * sizeof(int));
    int* ptr = (int*)carve((NN + 1) * sizeof(int));
    int* pos = (int*)carve((NN + 1) * sizeof(int));
    int* bsum = (int*)carve(256 * sizeof(int));
    int* offs = (int*)carve(256 * sizeof(int));
    int* srcadj = (int*)carve((size_t)(NEPU_MAX + NEPI_MAX) * sizeof(int));
    int* jit = (int*)carve((size_t)NEPU_MAX * sizeof(int));
    int* jpos1 = (int*)carve((size_t)NE * sizeof(int));
    int* einv = (int*)carve((size_t)NEPU_MAX * sizeof(int));
    float* dinv = (float*)carve(NN * sizeof(float));
    float4* Scur4 = (float4*)carve((size_t)NEPU_MAX * sizeof(float4));
    // contiguous zero-region: norm2 | wuA | wuB | wi  (one bulk memset)
    size_t zbeg = off;
    float2* norm2 = (float2*)carve((size_t)NEPU_MAX * sizeof(float2));
    float4* wuA = (float4*)carve((size_t)NEPU_MAX * sizeof(float4));
    float4* wuB = (float4*)carve((size_t)NEPU_MAX * sizeof(float4));
    float4* wi = (float4*)carve((size_t)NEPI_MAX * sizeof(float4));
    size_t zlen = off - zbeg;
    unsigned short* egoUA = (unsigned short*)carve((size_t)NUM_USER * DIM * 2);
    unsigned short* egoUB = (unsigned short*)carve((size_t)NUM_USER * DIM * 2);
    unsigned* cmbIA = (unsigned*)carve((size_t)NUM_ITEM * DIM * 4);
    unsigned* cmbIB = (unsigned*)carve((size_t)NUM_ITEM * DIM * 4);

    hipMemsetAsync(cnt, 0, (NN + 1) * sizeof(int), stream);
    hipMemsetAsync(einv, 0xFF, (size_t)NEPU_MAX * sizeof(int), stream);  // all -1
    hipMemsetAsync(ws + zbeg, 0, zlen, stream);

    k_setup<<<NB_INIT + NB_COUNT4, 256, 0, stream>>>(user, item, egoUA, cmbIA,
                                                     allemb, row0, col0, cnt);
    k_scan1<<<NBLK_SCAN, SCAN_CHUNK, 0, stream>>>(cnt, dinv, ptr, bsum);
    k_scan2<<<1, 256, 0, stream>>>(bsum, offs);
    k_scan3<<<(NN + 1 + 255) / 256, 256, 0, stream>>>(ptr, offs, pos);
    k_fill<<<(NE + 255) / 256, 256, 0, stream>>>(row0, col0, pos, ptr, srcadj,
                                                 jit, jpos1, einv);
    k_w0pad<<<NB_W0 + NB_PAD, 256, 0, stream>>>(S_in, row0, col0, einv, dinv,
                                                ptr, cnt, srcadj, norm2, wuA);

    // layer 0: fused user double-iteration, then item conv with w2
    k_user_layer<<<NUM_USER * 64 / 256, 256, 0, stream>>>(
        ptr, srcadj, (float*)wuA, norm2, jit, (float*)wi, (float*)wuB,
        (float*)wuB, (float*)Scur4, cmbIA, egoUB, allemb, 1, 0);
    k_item_layer<<<NUM_ITEM * 64 / 256, 256, 0, stream>>>(
        ptr, srcadj, (const float*)wi, egoUA, cmbIB, allemb, 1);
    // layer 1: fused user (final S), then item conv with w4
    k_user_layer<<<NUM_USER * 64 / 256, 256, 0, stream>>>(
        ptr, srcadj, (float*)wuB, norm2, jit, (float*)wi, (float*)wuA,
        (float*)wuA, (float*)Scur4, cmbIB, egoUA, allemb, 0, 1);
    k_item_layer<<<NUM_ITEM * 64 / 256, 256, 0, stream>>>(
        ptr, srcadj, (const float*)wi, egoUB, cmbIA, allemb, 0);

    k_sout<<<(NE + 255) / 256, 256, 0, stream>>>(Scur4, jpos1, Sfinal);
}

// Round 8
// 410.593 us; speedup vs baseline: 1.0895x; 1.0895x over previous
//
#include <hip/hip_runtime.h>

#define NUM_USER 60000
#define NUM_ITEM 40000
#define NN 100000
#define NE 500000
#define DIM 64
#define KF 4
#define SCAN_CHUNK 512
#define NBLK_SCAN ((NN + 1 + SCAN_CHUNK - 1) / SCAN_CHUNK)
// padded slot-count upper bounds (each node rounds up to multiple of 4)
#define NEPU_MAX (NE + 3 * NUM_USER)   // 680000 user-side slots max
#define NEPI_MAX (NE + 3 * NUM_ITEM)   // 620000 item-side slots max
#define MAXU_SLOTS 44                  // register-cached user path handles <=44 slots
#define NB_INIT (NN * 64 / 256)        // 25000 blocks: one wave per node
#define NB_COUNT4 ((NE / 4 + 255) / 256)
#define NB_W0 ((NEPU_MAX + 255) / 256)
#define NB_PAD ((NN + 255) / 256)

// sum within each 16-lane group (butterfly: all lanes get result)
__device__ __forceinline__ float red16(float v) {
    v += __shfl_xor(v, 1);
    v += __shfl_xor(v, 2);
    v += __shfl_xor(v, 4);
    v += __shfl_xor(v, 8);
    return v;
}

__device__ __forceinline__ float b2f(unsigned short u) {
    return __uint_as_float(((unsigned)u) << 16);
}
__device__ __forceinline__ unsigned short f2b(float x) {
    unsigned u = __float_as_uint(x);
    u = (u + 0x7fffu + ((u >> 16) & 1u)) >> 16;   // RNE
    return (unsigned short)u;
}
// combined item word: high16 = T (bf16 bits), low16 = ego (bf16 bits)
__device__ __forceinline__ float cvt_lo(unsigned c) { return __uint_as_float(c << 16); }
__device__ __forceinline__ float cvt_hi(unsigned c) { return __uint_as_float(c & 0xffff0000u); }
// pack hi16 halves of two combined words: lo16(out)=hi16(c0), hi16(out)=hi16(c1)
__device__ __forceinline__ unsigned packhi(unsigned c0, unsigned c1) {
#if defined(__has_builtin) && __has_builtin(__builtin_amdgcn_perm)
    return __builtin_amdgcn_perm(c1, c0, 0x07060302u);
#else
    return (c0 >> 16) | (c1 & 0xffff0000u);
#endif
}
// mixed-butterfly level: lane keeps the value whose slot-bit matches its lane bit
__device__ __forceinline__ float mixv(float x, float y, bool b, int m) {
    return (b ? y : x) + __shfl_xor(b ? x : y, m);
}

__device__ __forceinline__ float4 softmax4(float4 s) {
    float m = fmaxf(fmaxf(s.x, s.y), fmaxf(s.z, s.w));
    float e0 = __expf(s.x - m), e1 = __expf(s.y - m);
    float e2 = __expf(s.z - m), e3 = __expf(s.w - m);
    float inv = 1.0f / (e0 + e1 + e2 + e3);
    return make_float4(e0 * inv, e1 * inv, e2 * inv, e3 * inv);
}

// Fused per-slot S/weight update (single weight buffer: every access to a
// user slot is by its owning lane, read-before-write in program order).
// softmax(S_old) reconstructed as w*(1/n). snew = w*rn + dot.
// last: S4f <- snew (final output); else w' = n*softmax_k(snew) -> wu
// (+ wi item-order scatter only when writeWi: it=1's wi is never consumed).
__device__ __forceinline__ void fused_upd(int jj, int k, float dot, bool wr,
        float* __restrict__ wu, float* __restrict__ S4f,
        const float2* __restrict__ norm2, const int* __restrict__ jit,
        float* __restrict__ wiW, int last, int writeWi) {
    float w = wu[4 * jj + k];
    float2 nn = norm2[jj];
    float snew = fmaf(w, nn.y, dot);
    if (last) {
        if (wr) S4f[4 * jj + k] = snew;
        return;
    }
    float m2 = fmaxf(snew, __shfl_xor(snew, 16));
    m2 = fmaxf(m2, __shfl_xor(m2, 32));
    float e2 = __expf(snew - m2);
    float s2 = e2 + __shfl_xor(e2, 16);
    s2 += __shfl_xor(s2, 32);
    if (wr && nn.x > 0.0f) {
        float wn = nn.x * e2 * (1.0f / s2);
        wu[4 * jj + k] = wn;
        if (writeWi) wiW[4 * jit[jj] + k] = wn;
    }
}

// merged: blocks [0, NB_INIT) = per-node init; rest = 4-edge int4 degree count.
__global__ void k_setup(const float* __restrict__ user, const float* __restrict__ item,
                        unsigned short* __restrict__ egoU, unsigned* __restrict__ cmbI,
                        float* __restrict__ allemb, const int* __restrict__ row0,
                        const int* __restrict__ col0, int* __restrict__ cnt) {
    int b = blockIdx.x;
    if (b < NB_INIT) {
        int node = (b * 256 + threadIdx.x) >> 6;   // < NN by construction
        int lane = threadIdx.x & 63;
        int i = node * DIM + lane;
        if (node < NUM_USER) {
            float v = user[i];
            egoU[i] = f2b(v);
            allemb[i] = v;
        } else {
            float v = item[i - NUM_USER * DIM];
            allemb[i] = v;
            float ss = red16(v * v);
            float t = tanhf(v / fmaxf(sqrtf(ss), 1e-12f));
            cmbI[i - NUM_USER * DIM] = (((unsigned)f2b(t)) << 16) | (unsigned)f2b(v);
        }
    } else {
        int t = (b - NB_INIT) * 256 + threadIdx.x;
        if (t >= NE / 4) return;
        int4 r = ((const int4*)row0)[t];
        int4 c = ((const int4*)col0)[t];
        atomicAdd(&cnt[r.x], 1);
        atomicAdd(&cnt[r.y], 1);
        atomicAdd(&cnt[r.z], 1);
        atomicAdd(&cnt[r.w], 1);
        atomicAdd(&cnt[c.x], 1);
        atomicAdd(&cnt[c.y], 1);
        atomicAdd(&cnt[c.z], 1);
        atomicAdd(&cnt[c.w], 1);
    }
}

// --- 3-stage exclusive scan over padded counts -> ptr[NN+1]; dinv fused ---
__global__ void k_scan1(const int* __restrict__ cnt, float* __restrict__ dinv,
                        int* __restrict__ ptr, int* __restrict__ bsum) {
    __shared__ int sm[SCAN_CHUNK];
    int tid = threadIdx.x;
    int idx = blockIdx.x * SCAN_CHUNK + tid;
    int d = (idx < NN) ? cnt[idx] : 0;
    if (idx < NN) dinv[idx] = (d > 0) ? rsqrtf((float)d) : 0.0f;
    int x = (d + 3) & ~3;
    sm[tid] = x;
    __syncthreads();
    for (int off = 1; off < SCAN_CHUNK; off <<= 1) {
        int v = (tid >= off) ? sm[tid - off] : 0;
        __syncthreads();
        sm[tid] += v;
        __syncthreads();
    }
    if (idx <= NN) ptr[idx] = sm[tid] - x;
    if (tid == SCAN_CHUNK - 1) bsum[blockIdx.x] = sm[tid];
}

__global__ void k_scan2(int* __restrict__ bsum, int* __restrict__ offs) {
    __shared__ int sm[256];
    int tid = threadIdx.x;
    int x = (tid < NBLK_SCAN) ? bsum[tid] : 0;
    sm[tid] = x;
    __syncthreads();
    for (int off = 1; off < 256; off <<= 1) {
        int v = (tid >= off) ? sm[tid - off] : 0;
        __syncthreads();
        sm[tid] += v;
        __syncthreads();
    }
    if (tid < NBLK_SCAN) offs[tid] = sm[tid] - x;
}

// finalize scan; also replicate into pos (removes the D2D memcpy dispatch)
__global__ void k_scan3(int* __restrict__ ptr, const int* __restrict__ offs,
                        int* __restrict__ pos) {
    int idx = blockIdx.x * blockDim.x + threadIdx.x;
    if (idx > NN) return;
    int v = ptr[idx] + offs[idx / SCAN_CHUNK];
    ptr[idx] = v;
    pos[idx] = v;
}

// fill CSR. user-side slots [0, ptr[NUM_USER]); src ITEM-LOCAL pre-scaled <<6.
// jit[user_slot] = item-local slot of same edge; einv[user_slot] = edge id + 1
// (dummies stay 0 from the bulk zero memset).
__global__ void k_fill(const int* __restrict__ row0, const int* __restrict__ col0,
                       int* __restrict__ pos, const int* __restrict__ ptr,
                       int* __restrict__ srcadj, int* __restrict__ jit,
                       int* __restrict__ jpos1, int* __restrict__ einv) {
    int e = blockIdx.x * blockDim.x + threadIdx.x;
    if (e >= NE) return;
    int r = row0[e], c = col0[e];
    int ptrU = ptr[NUM_USER];
    int j1 = atomicAdd(&pos[r], 1);
    srcadj[j1] = (c - NUM_USER) << 6;
    jpos1[e] = j1;
    einv[j1] = e + 1;
    int j0 = atomicAdd(&pos[c], 1);
    srcadj[j0] = r << 6;
    jit[j1] = j0 - ptrU;
}

// merged: blocks [0, NB_W0) = slot-parallel weight init (norm {n,1/n} + w1,
// USER order only -- items never consume w1); rest = dummy-slot srcadj=0.
__global__ void k_w0pad(const float* __restrict__ Sin, const int* __restrict__ row0,
                        const int* __restrict__ col0, const int* __restrict__ einv,
                        const float* __restrict__ dinv, const int* __restrict__ ptr,
                        const int* __restrict__ cnt, int* __restrict__ srcadj,
                        float2* __restrict__ norm2, float4* __restrict__ wuA) {
    int b = blockIdx.x;
    if (b < NB_W0) {
        int j = b * 256 + threadIdx.x;
        if (j >= ptr[NUM_USER]) return;
        int e1 = einv[j];
        if (e1 == 0) return;   // dummy: stays zero
        int e = e1 - 1;
        float n = dinv[row0[e]] * dinv[col0[e]];
        float4 s = make_float4(Sin[e], Sin[NE + e], Sin[2 * NE + e], Sin[3 * NE + e]);
        float4 p = softmax4(s);
        norm2[j] = make_float2(n, 1.0f / n);
        wuA[j] = make_float4(n * p.x, n * p.y, n * p.z, n * p.w);
    } else {
        int n = (b - NB_W0) * 256 + threadIdx.x;
        if (n >= NN) return;
        int realend = ptr[n] + cnt[n];
        int end = ptr[n + 1];
        for (int j = realend; j < end; ++j) srcadj[j] = 0;
    }
}

// Scur4 (slot order, written by last conv) -> Sout [4][E] edge order
__global__ void k_sout(const float4* __restrict__ Scur4, const int* __restrict__ jpos1,
                       float* __restrict__ Sout) {
    int e = blockIdx.x * blockDim.x + threadIdx.x;
    if (e >= NE) return;
    float4 s = Scur4[jpos1[e]];
    Sout[e] = s.x;
    Sout[NE + e] = s.y;
    Sout[2 * NE + e] = s.z;
    Sout[3 * NE + e] = s.w;
}

// ---- user conv block macros: 16 outstanding gathers per issue point ----
// (srcadj values are pre-scaled by DIM)
#define UCONV16(JOFF, TP0) do { \
    int j = beg + (JOFF); \
    int4 sA = *(const int4*)(srcadj + j); \
    int4 sB = *(const int4*)(srcadj + j + 4); \
    int4 sC = *(const int4*)(srcadj + j + 8); \
    int4 sD = *(const int4*)(srcadj + j + 12); \
    unsigned c0 = cmbI[sA.x + lane]; \
    unsigned c1 = cmbI[sA.y + lane]; \
    unsigned c2 = cmbI[sA.z + lane]; \
    unsigned c3 = cmbI[sA.w + lane]; \
    unsigned c4 = cmbI[sB.x + lane]; \
    unsigned c5 = cmbI[sB.y + lane]; \
    unsigned c6 = cmbI[sB.z + lane]; \
    unsigned c7 = cmbI[sB.w + lane]; \
    unsigned c8 = cmbI[sC.x + lane]; \
    unsigned c9 = cmbI[sC.y + lane]; \
    unsigned c10 = cmbI[sC.z + lane]; \
    unsigned c11 = cmbI[sC.w + lane]; \
    unsigned c12 = cmbI[sD.x + lane]; \
    unsigned c13 = cmbI[sD.y + lane]; \
    unsigned c14 = cmbI[sD.z + lane]; \
    unsigned c15 = cmbI[sD.w + lane]; \
    a0 = fmaf(wu[4 * j + k], cvt_lo(c0), a0); \
    a1 = fmaf(wu[4 * j + 4 + k], cvt_lo(c1), a1); \
    a2 = fmaf(wu[4 * j + 8 + k], cvt_lo(c2), a2); \
    a3 = fmaf(wu[4 * j + 12 + k], cvt_lo(c3), a3); \
    a0 = fmaf(wu[4 * j + 16 + k], cvt_lo(c4), a0); \
    a1 = fmaf(wu[4 * j + 20 + k], cvt_lo(c5), a1); \
    a2 = fmaf(wu[4 * j + 24 + k], cvt_lo(c6), a2); \
    a3 = fmaf(wu[4 * j + 28 + k], cvt_lo(c7), a3); \
    a0 = fmaf(wu[4 * j + 32 + k], cvt_lo(c8), a0); \
    a1 = fmaf(wu[4 * j + 36 + k], cvt_lo(c9), a1); \
    a2 = fmaf(wu[4 * j + 40 + k], cvt_lo(c10), a2); \
    a3 = fmaf(wu[4 * j + 44 + k], cvt_lo(c11), a3); \
    a0 = fmaf(wu[4 * j + 48 + k], cvt_lo(c12), a0); \
    a1 = fmaf(wu[4 * j + 52 + k], cvt_lo(c13), a1); \
    a2 = fmaf(wu[4 * j + 56 + k], cvt_lo(c14), a2); \
    a3 = fmaf(wu[4 * j + 60 + k], cvt_lo(c15), a3); \
    tp[(TP0) + 0] = packhi(c0, c1); \
    tp[(TP0) + 1] = packhi(c2, c3); \
    tp[(TP0) + 2] = packhi(c4, c5); \
    tp[(TP0) + 3] = packhi(c6, c7); \
    tp[(TP0) + 4] = packhi(c8, c9); \
    tp[(TP0) + 5] = packhi(c10, c11); \
    tp[(TP0) + 6] = packhi(c12, c13); \
    tp[(TP0) + 7] = packhi(c14, c15); \
} while (0)

#define UCONV8(JOFF, TP0) do { \
    int j = beg + (JOFF); \
    int4 sA = *(const int4*)(srcadj + j); \
    int4 sB = *(const int4*)(srcadj + j + 4); \
    unsigned c0 = cmbI[sA.x + lane]; \
    unsigned c1 = cmbI[sA.y + lane]; \
    unsigned c2 = cmbI[sA.z + lane]; \
    unsigned c3 = cmbI[sA.w + lane]; \
    unsigned c4 = cmbI[sB.x + lane]; \
    unsigned c5 = cmbI[sB.y + lane]; \
    unsigned c6 = cmbI[sB.z + lane]; \
    unsigned c7 = cmbI[sB.w + lane]; \
    a0 = fmaf(wu[4 * j + k], cvt_lo(c0), a0); \
    a1 = fmaf(wu[4 * j + 4 + k], cvt_lo(c1), a1); \
    a2 = fmaf(wu[4 * j + 8 + k], cvt_lo(c2), a2); \
    a3 = fmaf(wu[4 * j + 12 + k], cvt_lo(c3), a3); \
    a0 = fmaf(wu[4 * j + 16 + k], cvt_lo(c4), a0); \
    a1 = fmaf(wu[4 * j + 20 + k], cvt_lo(c5), a1); \
    a2 = fmaf(wu[4 * j + 24 + k], cvt_lo(c6), a2); \
    a3 = fmaf(wu[4 * j + 28 + k], cvt_lo(c7), a3); \
    tp[(TP0) + 0] = packhi(c0, c1); \
    tp[(TP0) + 1] = packhi(c2, c3); \
    tp[(TP0) + 2] = packhi(c4, c5); \
    tp[(TP0) + 3] = packhi(c6, c7); \
} while (0)

#define UCONV4(JOFF, TP0) do { \
    int j = beg + (JOFF); \
    int4 sA = *(const int4*)(srcadj + j); \
    unsigned c0 = cmbI[sA.x + lane]; \
    unsigned c1 = cmbI[sA.y + lane]; \
    unsigned c2 = cmbI[sA.z + lane]; \
    unsigned c3 = cmbI[sA.w + lane]; \
    a0 = fmaf(wu[4 * j + k], cvt_lo(c0), a0); \
    a1 = fmaf(wu[4 * j + 4 + k], cvt_lo(c1), a1); \
    a2 = fmaf(wu[4 * j + 8 + k], cvt_lo(c2), a2); \
    a3 = fmaf(wu[4 * j + 12 + k], cvt_lo(c3), a3); \
    tp[(TP0) + 0] = packhi(c0, c1); \
    tp[(TP0) + 1] = packhi(c2, c3); \
} while (0)

// fused gather conv + routing score + S/weight update.
// wave per node; lane = dim, k = lane>>4 = factor.
// nlim: NUM_USER on non-layer-end dispatches (item conv output unused there),
// NN on layer-end. Weights: SINGLE buffer each side (slot ownership makes
// read-before-write safe); wi scattered only when flags&8 (it=0 dispatches).
// flags: 1 = layer end (allemb += acc), 4 = write next ego (items: +tanh T),
// 8 = scatter wi.
__global__ __launch_bounds__(256, 4) void k_conv_score(
        const int* __restrict__ ptr, const int* __restrict__ srcadj,
        float* __restrict__ wu, float* __restrict__ wi,
        float* __restrict__ S4f, const float2* __restrict__ norm2,
        const int* __restrict__ jit, const unsigned short* __restrict__ egoU,
        const unsigned* __restrict__ cmbI, unsigned short* __restrict__ xnextU,
        unsigned* __restrict__ cmbNext, float* __restrict__ allemb,
        int flags, int last, int nlim) {
    int node = (blockIdx.x * blockDim.x + threadIdx.x) >> 6;
    int lane = threadIdx.x & 63;
    if (node >= nlim) return;
    int beg = __builtin_amdgcn_readfirstlane(ptr[node]);
    int end = __builtin_amdgcn_readfirstlane(ptr[node + 1]);
    int count = end - beg;
    int k = lane >> 4;
    int writeWi = flags & 8;

    float a0 = 0.0f, a1 = 0.0f, a2 = 0.0f, a3 = 0.0f;

    if (node >= NUM_USER) {
        // ---- item side: conv only, 16-deep (runs only on layer-end) ----
        int ptrU = __builtin_amdgcn_readfirstlane(ptr[NUM_USER]);
        const float* wT = wi + (size_t)4 * (beg - ptrU);
        int t = 0;
        for (; t + 16 <= count; t += 16) {
            int4 sA = *(const int4*)(srcadj + beg + t);
            int4 sB = *(const int4*)(srcadj + beg + t + 4);
            int4 sC = *(const int4*)(srcadj + beg + t + 8);
            int4 sD = *(const int4*)(srcadj + beg + t + 12);
            a0 = fmaf(wT[4 * t + k], b2f(egoU[sA.x + lane]), a0);
            a1 = fmaf(wT[4 * t + 4 + k], b2f(egoU[sA.y + lane]), a1);
            a2 = fmaf(wT[4 * t + 8 + k], b2f(egoU[sA.z + lane]), a2);
            a3 = fmaf(wT[4 * t + 12 + k], b2f(egoU[sA.w + lane]), a3);
            a0 = fmaf(wT[4 * t + 16 + k], b2f(egoU[sB.x + lane]), a0);
            a1 = fmaf(wT[4 * t + 20 + k], b2f(egoU[sB.y + lane]), a1);
            a2 = fmaf(wT[4 * t + 24 + k], b2f(egoU[sB.z + lane]), a2);
            a3 = fmaf(wT[4 * t + 28 + k], b2f(egoU[sB.w + lane]), a3);
            a0 = fmaf(wT[4 * t + 32 + k], b2f(egoU[sC.x + lane]), a0);
            a1 = fmaf(wT[4 * t + 36 + k], b2f(egoU[sC.y + lane]), a1);
            a2 = fmaf(wT[4 * t + 40 + k], b2f(egoU[sC.z + lane]), a2);
            a3 = fmaf(wT[4 * t + 44 + k], b2f(egoU[sC.w + lane]), a3);
            a0 = fmaf(wT[4 * t + 48 + k], b2f(egoU[sD.x + lane]), a0);
            a1 = fmaf(wT[4 * t + 52 + k], b2f(egoU[sD.y + lane]), a1);
            a2 = fmaf(wT[4 * t + 56 + k], b2f(egoU[sD.z + lane]), a2);
            a3 = fmaf(wT[4 * t + 60 + k], b2f(egoU[sD.w + lane]), a3);
        }
        if (count & 8) {
            int4 sA = *(const int4*)(srcadj + beg + t);
            int4 sB = *(const int4*)(srcadj + beg + t + 4);
            a0 = fmaf(wT[4 * t + k], b2f(egoU[sA.x + lane]), a0);
            a1 = fmaf(wT[4 * t + 4 + k], b2f(egoU[sA.y + lane]), a1);
            a2 = fmaf(wT[4 * t + 8 + k], b2f(egoU[sA.z + lane]), a2);
            a3 = fmaf(wT[4 * t + 12 + k], b2f(egoU[sA.w + lane]), a3);
            a0 = fmaf(wT[4 * t + 16 + k], b2f(egoU[sB.x + lane]), a0);
            a1 = fmaf(wT[4 * t + 20 + k], b2f(egoU[sB.y + lane]), a1);
            a2 = fmaf(wT[4 * t + 24 + k], b2f(egoU[sB.z + lane]), a2);
            a3 = fmaf(wT[4 * t + 28 + k], b2f(egoU[sB.w + lane]), a3);
            t += 8;
        }
        if (count & 4) {
            int4 sA = *(const int4*)(srcadj + beg + t);
            a0 = fmaf(wT[4 * t + k], b2f(egoU[sA.x + lane]), a0);
            a1 = fmaf(wT[4 * t + 4 + k], b2f(egoU[sA.y + lane]), a1);
            a2 = fmaf(wT[4 * t + 8 + k], b2f(egoU[sA.z + lane]), a2);
            a3 = fmaf(wT[4 * t + 12 + k], b2f(egoU[sA.w + lane]), a3);
        }
        float acc = (a0 + a1) + (a2 + a3);
        if (flags & 1) {
            int i = node * DIM + lane;
            allemb[i] += acc;
            if (flags & 4) {
                float ss = red16(acc * acc);
                float tt = tanhf(acc / fmaxf(sqrtf(ss), 1e-12f));
                cmbNext[i - NUM_USER * DIM] =
                    (((unsigned)f2b(tt)) << 16) | (unsigned)f2b(acc);
            }
        }
        return;
    }

    // ---- user side: conv + routing score + fused S/w update ----
    unsigned tp[22];          // packed T cache: 2 slots/word, static-indexed
    bool big = count > MAXU_SLOTS;   // wave-uniform fallback (statistically never)
    int rem = count & 15;
    int rbase = count & ~15;

    if (!big) {
        if (count >= 16) UCONV16(0, 0);
        if (count >= 32) UCONV16(16, 8);
        if (rem & 8) UCONV8(rbase, 16);
        if (rem & 4) UCONV4(rbase + (rem & 8), 20);
    } else {
        for (int j = beg; j < end; j += 4) {
            int4 s = *(const int4*)(srcadj + j);
            a0 = fmaf(wu[4 * j + k], cvt_lo(cmbI[s.x + lane]), a0);
            a1 = fmaf(wu[4 * j + 4 + k], cvt_lo(cmbI[s.y + lane]), a1);
            a2 = fmaf(wu[4 * j + 8 + k], cvt_lo(cmbI[s.z + lane]), a2);
            a3 = fmaf(wu[4 * j + 12 + k], cvt_lo(cmbI[s.w + lane]), a3);
        }
    }
    float acc = (a0 + a1) + (a2 + a3);

    if (flags & 1) {
        int i = node * DIM + lane;
        allemb[i] += acc;
        if (flags & 4) xnextU[i] = f2b(acc);
    }

    // routing score from register cache + fused per-slot S/weight update
    float ssu = red16(acc * acc);
    float u = acc / fmaxf(sqrtf(ssu), 1e-12f);
    bool b0 = lane & 1;
    bool b1 = lane & 2;
    bool b2 = lane & 4;
    bool b3 = lane & 8;

    if (!big) {
#define USC16(JOFF, TP0) do { \
        int j = beg + (JOFF); \
        float p0 = u * __uint_as_float(tp[(TP0) + 0] << 16); \
        float p1 = u * __uint_as_float(tp[(TP0) + 0] & 0xffff0000u); \
        float p2 = u * __uint_as_float(tp[(TP0) + 1] << 16); \
        float p3 = u * __uint_as_float(tp[(TP0) + 1] & 0xffff0000u); \
        float p4 = u * __uint_as_float(tp[(TP0) + 2] << 16); \
        float p5 = u * __uint_as_float(tp[(TP0) + 2] & 0xffff0000u); \
        float p6 = u * __uint_as_float(tp[(TP0) + 3] << 16); \
        float p7 = u * __uint_as_float(tp[(TP0) + 3] & 0xffff0000u); \
        float p8 = u * __uint_as_float(tp[(TP0) + 4] << 16); \
        float p9 = u * __uint_as_float(tp[(TP0) + 4] & 0xffff0000u); \
        float p10 = u * __uint_as_float(tp[(TP0) + 5] << 16); \
        float p11 = u * __uint_as_float(tp[(TP0) + 5] & 0xffff0000u); \
        float p12 = u * __uint_as_float(tp[(TP0) + 6] << 16); \
        float p13 = u * __uint_as_float(tp[(TP0) + 6] & 0xffff0000u); \
        float p14 = u * __uint_as_float(tp[(TP0) + 7] << 16); \
        float p15 = u * __uint_as_float(tp[(TP0) + 7] & 0xffff0000u); \
        float q0 = mixv(p0, p1, b0, 1); \
        float q1 = mixv(p2, p3, b0, 1); \
        float q2 = mixv(p4, p5, b0, 1); \
        float q3 = mixv(p6, p7, b0, 1); \
        float q4 = mixv(p8, p9, b0, 1); \
        float q5 = mixv(p10, p11, b0, 1); \
        float q6 = mixv(p12, p13, b0, 1); \
        float q7 = mixv(p14, p15, b0, 1); \
        float r0 = mixv(q0, q1, b1, 2); \
        float r1 = mixv(q2, q3, b1, 2); \
        float r2 = mixv(q4, q5, b1, 2); \
        float r3 = mixv(q6, q7, b1, 2); \
        float s0 = mixv(r0, r1, b2, 4); \
        float s1 = mixv(r2, r3, b2, 4); \
        float t0 = mixv(s0, s1, b3, 8); \
        fused_upd(j + (lane & 15), k, t0, true, \
                  wu, S4f, norm2, jit, wi, last, writeWi); \
} while (0)
        if (count >= 16) USC16(0, 0);
        if (count >= 32) USC16(16, 8);
        if (rem & 8) {
            int j = beg + rbase;
            float p0 = u * __uint_as_float(tp[16] << 16);
            float p1 = u * __uint_as_float(tp[16] & 0xffff0000u);
            float p2 = u * __uint_as_float(tp[17] << 16);
            float p3 = u * __uint_as_float(tp[17] & 0xffff0000u);
            float p4 = u * __uint_as_float(tp[18] << 16);
            float p5 = u * __uint_as_float(tp[18] & 0xffff0000u);
            float p6 = u * __uint_as_float(tp[19] << 16);
            float p7 = u * __uint_as_float(tp[19] & 0xffff0000u);
            float q0 = mixv(p0, p1, b0, 1);
            float q1 = mixv(p2, p3, b0, 1);
            float q2 = mixv(p4, p5, b0, 1);
            float q3 = mixv(p6, p7, b0, 1);
            float r0 = mixv(q0, q1, b1, 2);
            float r1 = mixv(q2, q3, b1, 2);
            float t0 = mixv(r0, r1, b2, 4);
            t0 += __shfl_xor(t0, 8);
            fused_upd(j + (lane & 7), k, t0, !(lane & 8),
                      wu, S4f, norm2, jit, wi, last, writeWi);
        }
        if (rem & 4) {
            int j = beg + rbase + (rem & 8);
            float p0 = u * __uint_as_float(tp[20] << 16);
            float p1 = u * __uint_as_float(tp[20] & 0xffff0000u);
            float p2 = u * __uint_as_float(tp[21] << 16);
            float p3 = u * __uint_as_float(tp[21] & 0xffff0000u);
            float q0 = mixv(p0, p1, b0, 1);
            float q1 = mixv(p2, p3, b0, 1);
            float r0 = mixv(q0, q1, b1, 2);
            r0 += __shfl_xor(r0, 4);
            r0 += __shfl_xor(r0, 8);
            fused_upd(j + (lane & 3), k, r0, !(lane & 12),
                      wu, S4f, norm2, jit, wi, last, writeWi);
        }
    } else {
        for (int j = beg; j < end; j += 4) {
            int4 s = *(const int4*)(srcadj + j);
            float p0 = red16(u * cvt_hi(cmbI[s.x + lane]));
            float p1 = red16(u * cvt_hi(cmbI[s.y + lane]));
            float p2 = red16(u * cvt_hi(cmbI[s.z + lane]));
            float p3 = red16(u * cvt_hi(cmbI[s.w + lane]));
            int sl = lane & 3;
            float dv = p0;
            dv = (sl == 1) ? p1 : dv;
            dv = (sl == 2) ? p2 : dv;
            dv = (sl == 3) ? p3 : dv;
            fused_upd(j + sl, k, dv, !(lane & 12),
                      wu, S4f, norm2, jit, wi, last, writeWi);
        }
    }
}

extern "C" void kernel_launch(void* const* d_in, const int* in_sizes, int n_in,
                              void* d_out, int out_size, void* d_ws, size_t ws_size,
                              hipStream_t stream) {
    const float* user = (const float*)d_in[0];
    const float* item = (const float*)d_in[1];
    const float* S_in = (const float*)d_in[2];
    const int* edge = (const int*)d_in[3];
    const int* row0 = edge;
    const int* col0 = edge + NE;

    float* out = (float*)d_out;
    float* allemb = out;              // NN*DIM floats
    float* Sfinal = out + NN * DIM;   // KF*NE floats

    char* ws = (char*)d_ws;
    size_t off = 0;
    auto carve = [&](size_t bytes) { void* p = ws + off; off += (bytes + 255) & ~(size_t)255; return p; };
    int* ptr = (int*)carve((NN + 1) * sizeof(int));
    int* pos = (int*)carve((NN + 1) * sizeof(int));
    int* bsum = (int*)carve(256 * sizeof(int));
    int* offs = (int*)carve(256 * sizeof(int));
    int* srcadj = (int*)carve((size_t)(NEPU_MAX + NEPI_MAX) * sizeof(int));
    int* jit = (int*)carve((size_t)NEPU_MAX * sizeof(int));
    int* jpos1 = (int*)carve((size_t)NE * sizeof(int));
    float* dinv = (float*)carve(NN * sizeof(float));
    float4* Scur4 = (float4*)carve((size_t)NEPU_MAX * sizeof(float4));
    // contiguous zero-region: cnt | einv | norm2 | wu | wi  (ONE bulk memset)
    size_t zbeg = off;
    int* cnt = (int*)carve((NN + 1) * sizeof(int));
    int* einv = (int*)carve((size_t)NEPU_MAX * sizeof(int));
    float2* norm2 = (float2*)carve((size_t)NEPU_MAX * sizeof(float2));
    float4* wu = (float4*)carve((size_t)NEPU_MAX * sizeof(float4));
    float4* wi = (float4*)carve((size_t)NEPI_MAX * sizeof(float4));
    size_t zlen = off - zbeg;
    unsigned short* egoUA = (unsigned short*)carve((size_t)NUM_USER * DIM * 2);
    unsigned short* egoUB = (unsigned short*)carve((size_t)NUM_USER * DIM * 2);
    unsigned* cmbIA = (unsigned*)carve((size_t)NUM_ITEM * DIM * 4);
    unsigned* cmbIB = (unsigned*)carve((size_t)NUM_ITEM * DIM * 4);

    hipMemsetAsync(ws + zbeg, 0, zlen, stream);

    k_setup<<<NB_INIT + NB_COUNT4, 256, 0, stream>>>(user, item, egoUA, cmbIA,
                                                     allemb, row0, col0, cnt);
    k_scan1<<<NBLK_SCAN, SCAN_CHUNK, 0, stream>>>(cnt, dinv, ptr, bsum);
    k_scan2<<<1, 256, 0, stream>>>(bsum, offs);
    k_scan3<<<(NN + 1 + 255) / 256, 256, 0, stream>>>(ptr, offs, pos);
    k_fill<<<(NE + 255) / 256, 256, 0, stream>>>(row0, col0, pos, ptr, srcadj,
                                                 jit, jpos1, einv);
    k_w0pad<<<NB_W0 + NB_PAD, 256, 0, stream>>>(S_in, row0, col0, einv, dinv,
                                                ptr, cnt, srcadj, norm2, wu);

    unsigned short* egoU = egoUA;
    unsigned short* egoUn = egoUB;
    unsigned* cmbI = cmbIA;
    unsigned* cmbIn = cmbIB;
    for (int layer = 0; layer < 2; ++layer) {
        for (int it = 0; it < 2; ++it) {
            int flags = 0;
            if (it == 0) flags |= 8;                   // scatter wi (consumed at it=1)
            if (it == 1) flags |= 1;                   // layer end: allemb += acc
            if (it == 1 && layer == 0) flags |= 4;     // write next ego (+item T)
            int last = (layer == 1 && it == 1) ? 1 : 0;
            // non-layer-end: item x_new is never consumed -> user-only grid
            int nlim = (it == 1) ? NN : NUM_USER;
            k_conv_score<<<(nlim * 64 + 255) / 256, 256, 0, stream>>>(
                ptr, srcadj, (float*)wu, (float*)wi, (float*)Scur4, norm2, jit,
                egoU, cmbI, egoUn, cmbIn, allemb, flags, last, nlim);
        }
        unsigned short* t = egoU; egoU = egoUn; egoUn = t;
        unsigned* tc = cmbI; cmbI = cmbIn; cmbIn = tc;
    }
    k_sout<<<(NE + 255) / 256, 256, 0, stream>>>(Scur4, jpos1, Sfinal);
}

// Round 9
// 356.105 us; speedup vs baseline: 1.2562x; 1.1530x over previous
//
#include <hip/hip_runtime.h>

#define NUM_USER 60000
#define NUM_ITEM 40000
#define NN 100000
#define NE 500000
#define DIM 64
#define KF 4
#define SCAN_CHUNK 512
#define NBLK_SCAN ((NN + 1 + SCAN_CHUNK - 1) / SCAN_CHUNK)
// padded slot-count upper bounds (each node rounds up to multiple of 4)
#define NEPU_MAX (NE + 3 * NUM_USER)   // 680000 user-side slots max
#define NEPI_MAX (NE + 3 * NUM_ITEM)   // 620000 item-side slots max
#define MAXU_SLOTS 44                  // register-cached user path handles <=44 slots
#define NB_U4 (NUM_USER * DIM / 4 / 256)   // 3750 user-init blocks (float4/thread)
#define NB_I (NUM_ITEM / 16)               // 2500 item-init blocks (16 nodes/block)
#define NB_SETUP (NB_U4 + NB_I)            // 6250
#define EPB (NE / NB_SETUP)                // 80 edges counted per setup block

// sum within each 16-lane group (butterfly: all lanes get result)
__device__ __forceinline__ float red16(float v) {
    v += __shfl_xor(v, 1);
    v += __shfl_xor(v, 2);
    v += __shfl_xor(v, 4);
    v += __shfl_xor(v, 8);
    return v;
}

__device__ __forceinline__ float b2f(unsigned short u) {
    return __uint_as_float(((unsigned)u) << 16);
}
__device__ __forceinline__ unsigned short f2b(float x) {
    unsigned u = __float_as_uint(x);
    u = (u + 0x7fffu + ((u >> 16) & 1u)) >> 16;   // RNE
    return (unsigned short)u;
}
// combined item word: high16 = T (bf16 bits), low16 = ego (bf16 bits)
__device__ __forceinline__ float cvt_lo(unsigned c) { return __uint_as_float(c << 16); }
__device__ __forceinline__ float cvt_hi(unsigned c) { return __uint_as_float(c & 0xffff0000u); }
// pack hi16 halves of two combined words: lo16(out)=hi16(c0), hi16(out)=hi16(c1)
__device__ __forceinline__ unsigned packhi(unsigned c0, unsigned c1) {
#if defined(__has_builtin) && __has_builtin(__builtin_amdgcn_perm)
    return __builtin_amdgcn_perm(c1, c0, 0x07060302u);
#else
    return (c0 >> 16) | (c1 & 0xffff0000u);
#endif
}
// mixed-butterfly level: lane keeps the value whose slot-bit matches its lane bit
__device__ __forceinline__ float mixv(float x, float y, bool b, int m) {
    return (b ? y : x) + __shfl_xor(b ? x : y, m);
}

__device__ __forceinline__ float4 softmax4(float4 s) {
    float m = fmaxf(fmaxf(s.x, s.y), fmaxf(s.z, s.w));
    float e0 = __expf(s.x - m), e1 = __expf(s.y - m);
    float e2 = __expf(s.z - m), e3 = __expf(s.w - m);
    float inv = 1.0f / (e0 + e1 + e2 + e3);
    return make_float4(e0 * inv, e1 * inv, e2 * inv, e3 * inv);
}

// Fused per-slot S/weight update (single weight buffer: every access to a
// user slot is by its owning lane, read-before-write in program order).
// softmax(S_old) reconstructed as w*(1/n). snew = w*rn + dot.
// last: S4f <- snew (final output); else w' = n*softmax_k(snew) -> wu
// (+ wi item-order scatter only when writeWi: it=1's wi is never consumed).
__device__ __forceinline__ void fused_upd(int jj, int k, float dot, bool wr,
        float* __restrict__ wu, float* __restrict__ S4f,
        const float2* __restrict__ norm2, const int* __restrict__ jit,
        float* __restrict__ wiW, int last, int writeWi) {
    float w = wu[4 * jj + k];
    float2 nn = norm2[jj];
    float snew = fmaf(w, nn.y, dot);
    if (last) {
        if (wr) S4f[4 * jj + k] = snew;
        return;
    }
    float m2 = fmaxf(snew, __shfl_xor(snew, 16));
    m2 = fmaxf(m2, __shfl_xor(m2, 32));
    float e2 = __expf(snew - m2);
    float s2 = e2 + __shfl_xor(e2, 16);
    s2 += __shfl_xor(s2, 32);
    if (wr && nn.x > 0.0f) {
        float wn = nn.x * e2 * (1.0f / s2);
        wu[4 * jj + k] = wn;
        if (writeWi) wiW[4 * jit[jj] + k] = wn;
    }
}

// init (vectorized 4 dims/thread) + DISTRIBUTED degree count (80 edges/block,
// threads 0..159 one endpoint each -- atomics issue from 25k waves and hide
// under the streaming init instead of a low-occupancy 489-block tail).
__global__ void k_setup(const float* __restrict__ user, const float* __restrict__ item,
                        unsigned short* __restrict__ egoU, unsigned* __restrict__ cmbI,
                        float* __restrict__ allemb, const int* __restrict__ row0,
                        const int* __restrict__ col0, int* __restrict__ cnt) {
    int b = blockIdx.x, t = threadIdx.x;
    int ebase = b * EPB;
    if (t < EPB) atomicAdd(&cnt[row0[ebase + t]], 1);
    else if (t < 2 * EPB) atomicAdd(&cnt[col0[ebase + t - EPB]], 1);
    if (b < NB_U4) {
        // user: pure streaming copy, float4/thread
        int idx = (b * 256 + t) * 4;
        float4 v = *(const float4*)(user + idx);
        ushort4 e;
        e.x = f2b(v.x); e.y = f2b(v.y); e.z = f2b(v.z); e.w = f2b(v.w);
        *(ushort4*)(egoU + idx) = e;
        *(float4*)(allemb + idx) = v;
    } else {
        // item: 16 lanes/node, float4/lane; 16-dim norm = 4-lane reduce
        int bb = b - NB_U4;
        int lane = t & 63;
        int nodeI = bb * 16 + ((t >> 6) << 2) + (lane >> 4);
        int idx = nodeI * DIM + (lane & 15) * 4;
        float4 v = *(const float4*)(item + idx);
        float ss = v.x * v.x + v.y * v.y + v.z * v.z + v.w * v.w;
        ss += __shfl_xor(ss, 1);
        ss += __shfl_xor(ss, 2);
        float rinv = 1.0f / fmaxf(sqrtf(ss), 1e-12f);
        uint4 o;
        o.x = (((unsigned)f2b(tanhf(v.x * rinv))) << 16) | (unsigned)f2b(v.x);
        o.y = (((unsigned)f2b(tanhf(v.y * rinv))) << 16) | (unsigned)f2b(v.y);
        o.z = (((unsigned)f2b(tanhf(v.z * rinv))) << 16) | (unsigned)f2b(v.z);
        o.w = (((unsigned)f2b(tanhf(v.w * rinv))) << 16) | (unsigned)f2b(v.w);
        *(uint4*)(cmbI + idx) = o;
        *(float4*)(allemb + NUM_USER * DIM + idx) = v;
    }
}

// --- 3-stage exclusive scan over padded counts -> ptr[NN+1]; dinv fused ---
__global__ void k_scan1(const int* __restrict__ cnt, float* __restrict__ dinv,
                        int* __restrict__ ptr, int* __restrict__ bsum) {
    __shared__ int sm[SCAN_CHUNK];
    int tid = threadIdx.x;
    int idx = blockIdx.x * SCAN_CHUNK + tid;
    int d = (idx < NN) ? cnt[idx] : 0;
    if (idx < NN) dinv[idx] = (d > 0) ? rsqrtf((float)d) : 0.0f;
    int x = (d + 3) & ~3;
    sm[tid] = x;
    __syncthreads();
    for (int off = 1; off < SCAN_CHUNK; off <<= 1) {
        int v = (tid >= off) ? sm[tid - off] : 0;
        __syncthreads();
        sm[tid] += v;
        __syncthreads();
    }
    if (idx <= NN) ptr[idx] = sm[tid] - x;
    if (tid == SCAN_CHUNK - 1) bsum[blockIdx.x] = sm[tid];
}

__global__ void k_scan2(int* __restrict__ bsum, int* __restrict__ offs) {
    __shared__ int sm[256];
    int tid = threadIdx.x;
    int x = (tid < NBLK_SCAN) ? bsum[tid] : 0;
    sm[tid] = x;
    __syncthreads();
    for (int off = 1; off < 256; off <<= 1) {
        int v = (tid >= off) ? sm[tid - off] : 0;
        __syncthreads();
        sm[tid] += v;
        __syncthreads();
    }
    if (tid < NBLK_SCAN) offs[tid] = sm[tid] - x;
}

// finalize scan; replicate into pos; fill dummy-slot srcadj (end computable
// locally from cnt: realend = v+d, end = v+((d+3)&~3))
__global__ void k_scan3(int* __restrict__ ptr, const int* __restrict__ offs,
                        int* __restrict__ pos, const int* __restrict__ cnt,
                        int* __restrict__ srcadj) {
    int idx = blockIdx.x * blockDim.x + threadIdx.x;
    if (idx > NN) return;
    int v = ptr[idx] + offs[idx / SCAN_CHUNK];
    ptr[idx] = v;
    pos[idx] = v;
    if (idx < NN) {
        int d = cnt[idx];
        int end = v + ((d + 3) & ~3);
        for (int j = v + d; j < end; ++j) srcadj[j] = 0;
    }
}

// fill CSR + FUSED w0: thread owns edge e and its user slot j1, so norm2/wu
// init happens here with COALESCED Sin reads (was 4 random lines/slot via einv).
// user-side slots [0, ptr[NUM_USER]); src ITEM-LOCAL pre-scaled <<6.
__global__ void k_fillw0(const int* __restrict__ row0, const int* __restrict__ col0,
                         const float* __restrict__ Sin, const float* __restrict__ dinv,
                         int* __restrict__ pos, const int* __restrict__ ptr,
                         int* __restrict__ srcadj, int* __restrict__ jit,
                         int* __restrict__ jpos1, float2* __restrict__ norm2,
                         float4* __restrict__ wu) {
    int e = blockIdx.x * blockDim.x + threadIdx.x;
    if (e >= NE) return;
    int r = row0[e], c = col0[e];
    int ptrU = ptr[NUM_USER];
    int j1 = atomicAdd(&pos[r], 1);
    int j0 = atomicAdd(&pos[c], 1);
    srcadj[j1] = (c - NUM_USER) << 6;
    srcadj[j0] = r << 6;
    jit[j1] = j0 - ptrU;
    jpos1[e] = j1;
    float n = dinv[r] * dinv[c];
    float4 s = make_float4(Sin[e], Sin[NE + e], Sin[2 * NE + e], Sin[3 * NE + e]);
    float4 p = softmax4(s);
    norm2[j1] = make_float2(n, 1.0f / n);
    wu[j1] = make_float4(n * p.x, n * p.y, n * p.z, n * p.w);
}

// Scur4 (slot order, written by last conv) -> Sout [4][E] edge order
__global__ void k_sout(const float4* __restrict__ Scur4, const int* __restrict__ jpos1,
                       float* __restrict__ Sout) {
    int e = blockIdx.x * blockDim.x + threadIdx.x;
    if (e >= NE) return;
    float4 s = Scur4[jpos1[e]];
    Sout[e] = s.x;
    Sout[NE + e] = s.y;
    Sout[2 * NE + e] = s.z;
    Sout[3 * NE + e] = s.w;
}

// ---- user conv block macros: 16 outstanding gathers per issue point ----
// (srcadj values are pre-scaled by DIM)
#define UCONV16(JOFF, TP0) do { \
    int j = beg + (JOFF); \
    int4 sA = *(const int4*)(srcadj + j); \
    int4 sB = *(const int4*)(srcadj + j + 4); \
    int4 sC = *(const int4*)(srcadj + j + 8); \
    int4 sD = *(const int4*)(srcadj + j + 12); \
    unsigned c0 = cmbI[sA.x + lane]; \
    unsigned c1 = cmbI[sA.y + lane]; \
    unsigned c2 = cmbI[sA.z + lane]; \
    unsigned c3 = cmbI[sA.w + lane]; \
    unsigned c4 = cmbI[sB.x + lane]; \
    unsigned c5 = cmbI[sB.y + lane]; \
    unsigned c6 = cmbI[sB.z + lane]; \
    unsigned c7 = cmbI[sB.w + lane]; \
    unsigned c8 = cmbI[sC.x + lane]; \
    unsigned c9 = cmbI[sC.y + lane]; \
    unsigned c10 = cmbI[sC.z + lane]; \
    unsigned c11 = cmbI[sC.w + lane]; \
    unsigned c12 = cmbI[sD.x + lane]; \
    unsigned c13 = cmbI[sD.y + lane]; \
    unsigned c14 = cmbI[sD.z + lane]; \
    unsigned c15 = cmbI[sD.w + lane]; \
    a0 = fmaf(wu[4 * j + k], cvt_lo(c0), a0); \
    a1 = fmaf(wu[4 * j + 4 + k], cvt_lo(c1), a1); \
    a2 = fmaf(wu[4 * j + 8 + k], cvt_lo(c2), a2); \
    a3 = fmaf(wu[4 * j + 12 + k], cvt_lo(c3), a3); \
    a0 = fmaf(wu[4 * j + 16 + k], cvt_lo(c4), a0); \
    a1 = fmaf(wu[4 * j + 20 + k], cvt_lo(c5), a1); \
    a2 = fmaf(wu[4 * j + 24 + k], cvt_lo(c6), a2); \
    a3 = fmaf(wu[4 * j + 28 + k], cvt_lo(c7), a3); \
    a0 = fmaf(wu[4 * j + 32 + k], cvt_lo(c8), a0); \
    a1 = fmaf(wu[4 * j + 36 + k], cvt_lo(c9), a1); \
    a2 = fmaf(wu[4 * j + 40 + k], cvt_lo(c10), a2); \
    a3 = fmaf(wu[4 * j + 44 + k], cvt_lo(c11), a3); \
    a0 = fmaf(wu[4 * j + 48 + k], cvt_lo(c12), a0); \
    a1 = fmaf(wu[4 * j + 52 + k], cvt_lo(c13), a1); \
    a2 = fmaf(wu[4 * j + 56 + k], cvt_lo(c14), a2); \
    a3 = fmaf(wu[4 * j + 60 + k], cvt_lo(c15), a3); \
    tp[(TP0) + 0] = packhi(c0, c1); \
    tp[(TP0) + 1] = packhi(c2, c3); \
    tp[(TP0) + 2] = packhi(c4, c5); \
    tp[(TP0) + 3] = packhi(c6, c7); \
    tp[(TP0) + 4] = packhi(c8, c9); \
    tp[(TP0) + 5] = packhi(c10, c11); \
    tp[(TP0) + 6] = packhi(c12, c13); \
    tp[(TP0) + 7] = packhi(c14, c15); \
} while (0)

#define UCONV8(JOFF, TP0) do { \
    int j = beg + (JOFF); \
    int4 sA = *(const int4*)(srcadj + j); \
    int4 sB = *(const int4*)(srcadj + j + 4); \
    unsigned c0 = cmbI[sA.x + lane]; \
    unsigned c1 = cmbI[sA.y + lane]; \
    unsigned c2 = cmbI[sA.z + lane]; \
    unsigned c3 = cmbI[sA.w + lane]; \
    unsigned c4 = cmbI[sB.x + lane]; \
    unsigned c5 = cmbI[sB.y + lane]; \
    unsigned c6 = cmbI[sB.z + lane]; \
    unsigned c7 = cmbI[sB.w + lane]; \
    a0 = fmaf(wu[4 * j + k], cvt_lo(c0), a0); \
    a1 = fmaf(wu[4 * j + 4 + k], cvt_lo(c1), a1); \
    a2 = fmaf(wu[4 * j + 8 + k], cvt_lo(c2), a2); \
    a3 = fmaf(wu[4 * j + 12 + k], cvt_lo(c3), a3); \
    a0 = fmaf(wu[4 * j + 16 + k], cvt_lo(c4), a0); \
    a1 = fmaf(wu[4 * j + 20 + k], cvt_lo(c5), a1); \
    a2 = fmaf(wu[4 * j + 24 + k], cvt_lo(c6), a2); \
    a3 = fmaf(wu[4 * j + 28 + k], cvt_lo(c7), a3); \
    tp[(TP0) + 0] = packhi(c0, c1); \
    tp[(TP0) + 1] = packhi(c2, c3); \
    tp[(TP0) + 2] = packhi(c4, c5); \
    tp[(TP0) + 3] = packhi(c6, c7); \
} while (0)

#define UCONV4(JOFF, TP0) do { \
    int j = beg + (JOFF); \
    int4 sA = *(const int4*)(srcadj + j); \
    unsigned c0 = cmbI[sA.x + lane]; \
    unsigned c1 = cmbI[sA.y + lane]; \
    unsigned c2 = cmbI[sA.z + lane]; \
    unsigned c3 = cmbI[sA.w + lane]; \
    a0 = fmaf(wu[4 * j + k], cvt_lo(c0), a0); \
    a1 = fmaf(wu[4 * j + 4 + k], cvt_lo(c1), a1); \
    a2 = fmaf(wu[4 * j + 8 + k], cvt_lo(c2), a2); \
    a3 = fmaf(wu[4 * j + 12 + k], cvt_lo(c3), a3); \
    tp[(TP0) + 0] = packhi(c0, c1); \
    tp[(TP0) + 1] = packhi(c2, c3); \
} while (0)

// fused gather conv + routing score + S/weight update.
// wave per node; lane = dim, k = lane>>4 = factor.
// nlim: NUM_USER on non-layer-end dispatches (item conv output unused there),
// NN on layer-end. Weights: SINGLE buffer each side (slot ownership makes
// read-before-write safe); wi scattered only when flags&8 (it=0 dispatches).
// flags: 1 = layer end (allemb += acc), 4 = write next ego (items: +tanh T),
// 8 = scatter wi.
__global__ __launch_bounds__(256, 4) void k_conv_score(
        const int* __restrict__ ptr, const int* __restrict__ srcadj,
        float* __restrict__ wu, float* __restrict__ wi,
        float* __restrict__ S4f, const float2* __restrict__ norm2,
        const int* __restrict__ jit, const unsigned short* __restrict__ egoU,
        const unsigned* __restrict__ cmbI, unsigned short* __restrict__ xnextU,
        unsigned* __restrict__ cmbNext, float* __restrict__ allemb,
        int flags, int last, int nlim) {
    int node = (blockIdx.x * blockDim.x + threadIdx.x) >> 6;
    int lane = threadIdx.x & 63;
    if (node >= nlim) return;
    int beg = __builtin_amdgcn_readfirstlane(ptr[node]);
    int end = __builtin_amdgcn_readfirstlane(ptr[node + 1]);
    int count = end - beg;
    int k = lane >> 4;
    int writeWi = flags & 8;

    float a0 = 0.0f, a1 = 0.0f, a2 = 0.0f, a3 = 0.0f;

    if (node >= NUM_USER) {
        // ---- item side: conv only, 16-deep (runs only on layer-end) ----
        int ptrU = __builtin_amdgcn_readfirstlane(ptr[NUM_USER]);
        const float* wT = wi + (size_t)4 * (beg - ptrU);
        int t = 0;
        for (; t + 16 <= count; t += 16) {
            int4 sA = *(const int4*)(srcadj + beg + t);
            int4 sB = *(const int4*)(srcadj + beg + t + 4);
            int4 sC = *(const int4*)(srcadj + beg + t + 8);
            int4 sD = *(const int4*)(srcadj + beg + t + 12);
            a0 = fmaf(wT[4 * t + k], b2f(egoU[sA.x + lane]), a0);
            a1 = fmaf(wT[4 * t + 4 + k], b2f(egoU[sA.y + lane]), a1);
            a2 = fmaf(wT[4 * t + 8 + k], b2f(egoU[sA.z + lane]), a2);
            a3 = fmaf(wT[4 * t + 12 + k], b2f(egoU[sA.w + lane]), a3);
            a0 = fmaf(wT[4 * t + 16 + k], b2f(egoU[sB.x + lane]), a0);
            a1 = fmaf(wT[4 * t + 20 + k], b2f(egoU[sB.y + lane]), a1);
            a2 = fmaf(wT[4 * t + 24 + k], b2f(egoU[sB.z + lane]), a2);
            a3 = fmaf(wT[4 * t + 28 + k], b2f(egoU[sB.w + lane]), a3);
            a0 = fmaf(wT[4 * t + 32 + k], b2f(egoU[sC.x + lane]), a0);
            a1 = fmaf(wT[4 * t + 36 + k], b2f(egoU[sC.y + lane]), a1);
            a2 = fmaf(wT[4 * t + 40 + k], b2f(egoU[sC.z + lane]), a2);
            a3 = fmaf(wT[4 * t + 44 + k], b2f(egoU[sC.w + lane]), a3);
            a0 = fmaf(wT[4 * t + 48 + k], b2f(egoU[sD.x + lane]), a0);
            a1 = fmaf(wT[4 * t + 52 + k], b2f(egoU[sD.y + lane]), a1);
            a2 = fmaf(wT[4 * t + 56 + k], b2f(egoU[sD.z + lane]), a2);
            a3 = fmaf(wT[4 * t + 60 + k], b2f(egoU[sD.w + lane]), a3);
        }
        if (count & 8) {
            int4 sA = *(const int4*)(srcadj + beg + t);
            int4 sB = *(const int4*)(srcadj + beg + t + 4);
            a0 = fmaf(wT[4 * t + k], b2f(egoU[sA.x + lane]), a0);
            a1 = fmaf(wT[4 * t + 4 + k], b2f(egoU[sA.y + lane]), a1);
            a2 = fmaf(wT[4 * t + 8 + k], b2f(egoU[sA.z + lane]), a2);
            a3 = fmaf(wT[4 * t + 12 + k], b2f(egoU[sA.w + lane]), a3);
            a0 = fmaf(wT[4 * t + 16 + k], b2f(egoU[sB.x + lane]), a0);
            a1 = fmaf(wT[4 * t + 20 + k], b2f(egoU[sB.y + lane]), a1);
            a2 = fmaf(wT[4 * t + 24 + k], b2f(egoU[sB.z + lane]), a2);
            a3 = fmaf(wT[4 * t + 28 + k], b2f(egoU[sB.w + lane]), a3);
            t += 8;
        }
        if (count & 4) {
            int4 sA = *(const int4*)(srcadj + beg + t);
            a0 = fmaf(wT[4 * t + k], b2f(egoU[sA.x + lane]), a0);
            a1 = fmaf(wT[4 * t + 4 + k], b2f(egoU[sA.y + lane]), a1);
            a2 = fmaf(wT[4 * t + 8 + k], b2f(egoU[sA.z + lane]), a2);
            a3 = fmaf(wT[4 * t + 12 + k], b2f(egoU[sA.w + lane]), a3);
        }
        float acc = (a0 + a1) + (a2 + a3);
        if (flags & 1) {
            int i = node * DIM + lane;
            allemb[i] += acc;
            if (flags & 4) {
                float ss = red16(acc * acc);
                float tt = tanhf(acc / fmaxf(sqrtf(ss), 1e-12f));
                cmbNext[i - NUM_USER * DIM] =
                    (((unsigned)f2b(tt)) << 16) | (unsigned)f2b(acc);
            }
        }
        return;
    }

    // ---- user side: conv + routing score + fused S/w update ----
    unsigned tp[22];          // packed T cache: 2 slots/word, static-indexed
    bool big = count > MAXU_SLOTS;   // wave-uniform fallback (statistically never)
    int rem = count & 15;
    int rbase = count & ~15;

    if (!big) {
        if (count >= 16) UCONV16(0, 0);
        if (count >= 32) UCONV16(16, 8);
        if (rem & 8) UCONV8(rbase, 16);
        if (rem & 4) UCONV4(rbase + (rem & 8), 20);
    } else {
        for (int j = beg; j < end; j += 4) {
            int4 s = *(const int4*)(srcadj + j);
            a0 = fmaf(wu[4 * j + k], cvt_lo(cmbI[s.x + lane]), a0);
            a1 = fmaf(wu[4 * j + 4 + k], cvt_lo(cmbI[s.y + lane]), a1);
            a2 = fmaf(wu[4 * j + 8 + k], cvt_lo(cmbI[s.z + lane]), a2);
            a3 = fmaf(wu[4 * j + 12 + k], cvt_lo(cmbI[s.w + lane]), a3);
        }
    }
    float acc = (a0 + a1) + (a2 + a3);

    if (flags & 1) {
        int i = node * DIM + lane;
        allemb[i] += acc;
        if (flags & 4) xnextU[i] = f2b(acc);
    }

    // routing score from register cache + fused per-slot S/weight update
    float ssu = red16(acc * acc);
    float u = acc / fmaxf(sqrtf(ssu), 1e-12f);
    bool b0 = lane & 1;
    bool b1 = lane & 2;
    bool b2 = lane & 4;
    bool b3 = lane & 8;

    if (!big) {
#define USC16(JOFF, TP0) do { \
        int j = beg + (JOFF); \
        float p0 = u * __uint_as_float(tp[(TP0) + 0] << 16); \
        float p1 = u * __uint_as_float(tp[(TP0) + 0] & 0xffff0000u); \
        float p2 = u * __uint_as_float(tp[(TP0) + 1] << 16); \
        float p3 = u * __uint_as_float(tp[(TP0) + 1] & 0xffff0000u); \
        float p4 = u * __uint_as_float(tp[(TP0) + 2] << 16); \
        float p5 = u * __uint_as_float(tp[(TP0) + 2] & 0xffff0000u); \
        float p6 = u * __uint_as_float(tp[(TP0) + 3] << 16); \
        float p7 = u * __uint_as_float(tp[(TP0) + 3] & 0xffff0000u); \
        float p8 = u * __uint_as_float(tp[(TP0) + 4] << 16); \
        float p9 = u * __uint_as_float(tp[(TP0) + 4] & 0xffff0000u); \
        float p10 = u * __uint_as_float(tp[(TP0) + 5] << 16); \
        float p11 = u * __uint_as_float(tp[(TP0) + 5] & 0xffff0000u); \
        float p12 = u * __uint_as_float(tp[(TP0) + 6] << 16); \
        float p13 = u * __uint_as_float(tp[(TP0) + 6] & 0xffff0000u); \
        float p14 = u * __uint_as_float(tp[(TP0) + 7] << 16); \
        float p15 = u * __uint_as_float(tp[(TP0) + 7] & 0xffff0000u); \
        float q0 = mixv(p0, p1, b0, 1); \
        float q1 = mixv(p2, p3, b0, 1); \
        float q2 = mixv(p4, p5, b0, 1); \
        float q3 = mixv(p6, p7, b0, 1); \
        float q4 = mixv(p8, p9, b0, 1); \
        float q5 = mixv(p10, p11, b0, 1); \
        float q6 = mixv(p12, p13, b0, 1); \
        float q7 = mixv(p14, p15, b0, 1); \
        float r0 = mixv(q0, q1, b1, 2); \
        float r1 = mixv(q2, q3, b1, 2); \
        float r2 = mixv(q4, q5, b1, 2); \
        float r3 = mixv(q6, q7, b1, 2); \
        float s0 = mixv(r0, r1, b2, 4); \
        float s1 = mixv(r2, r3, b2, 4); \
        float t0 = mixv(s0, s1, b3, 8); \
        fused_upd(j + (lane & 15), k, t0, true, \
                  wu, S4f, norm2, jit, wi, last, writeWi); \
} while (0)
        if (count >= 16) USC16(0, 0);
        if (count >= 32) USC16(16, 8);
        if (rem & 8) {
            int j = beg + rbase;
            float p0 = u * __uint_as_float(tp[16] << 16);
            float p1 = u * __uint_as_float(tp[16] & 0xffff0000u);
            float p2 = u * __uint_as_float(tp[17] << 16);
            float p3 = u * __uint_as_float(tp[17] & 0xffff0000u);
            float p4 = u * __uint_as_float(tp[18] << 16);
            float p5 = u * __uint_as_float(tp[18] & 0xffff0000u);
            float p6 = u * __uint_as_float(tp[19] << 16);
            float p7 = u * __uint_as_float(tp[19] & 0xffff0000u);
            float q0 = mixv(p0, p1, b0, 1);
            float q1 = mixv(p2, p3, b0, 1);
            float q2 = mixv(p4, p5, b0, 1);
            float q3 = mixv(p6, p7, b0, 1);
            float r0 = mixv(q0, q1, b1, 2);
            float r1 = mixv(q2, q3, b1, 2);
            float t0 = mixv(r0, r1, b2, 4);
            t0 += __shfl_xor(t0, 8);
            fused_upd(j + (lane & 7), k, t0, !(lane & 8),
                      wu, S4f, norm2, jit, wi, last, writeWi);
        }
        if (rem & 4) {
            int j = beg + rbase + (rem & 8);
            float p0 = u * __uint_as_float(tp[20] << 16);
            float p1 = u * __uint_as_float(tp[20] & 0xffff0000u);
            float p2 = u * __uint_as_float(tp[21] << 16);
            float p3 = u * __uint_as_float(tp[21] & 0xffff0000u);
            float q0 = mixv(p0, p1, b0, 1);
            float q1 = mixv(p2, p3, b0, 1);
            float r0 = mixv(q0, q1, b1, 2);
            r0 += __shfl_xor(r0, 4);
            r0 += __shfl_xor(r0, 8);
            fused_upd(j + (lane & 3), k, r0, !(lane & 12),
                      wu, S4f, norm2, jit, wi, last, writeWi);
        }
    } else {
        for (int j = beg; j < end; j += 4) {
            int4 s = *(const int4*)(srcadj + j);
            float p0 = red16(u * cvt_hi(cmbI[s.x + lane]));
            float p1 = red16(u * cvt_hi(cmbI[s.y + lane]));
            float p2 = red16(u * cvt_hi(cmbI[s.z + lane]));
            float p3 = red16(u * cvt_hi(cmbI[s.w + lane]));
            int sl = lane & 3;
            float dv = p0;
            dv = (sl == 1) ? p1 : dv;
            dv = (sl == 2) ? p2 : dv;
            dv = (sl == 3) ? p3 : dv;
            fused_upd(j + sl, k, dv, !(lane & 12),
                      wu, S4f, norm2, jit, wi, last, writeWi);
        }
    }
}

extern "C" void kernel_launch(void* const* d_in, const int* in_sizes, int n_in,
                              void* d_out, int out_size, void* d_ws, size_t ws_size,
                              hipStream_t stream) {
    const float* user = (const float*)d_in[0];
    const float* item = (const float*)d_in[1];
    const float* S_in = (const float*)d_in[2];
    const int* edge = (const int*)d_in[3];
    const int* row0 = edge;
    const int* col0 = edge + NE;

    float* out = (float*)d_out;
    float* allemb = out;              // NN*DIM floats
    float* Sfinal = out + NN * DIM;   // KF*NE floats

    char* ws = (char*)d_ws;
    size_t off = 0;
    auto carve = [&](size_t bytes) { void* p = ws + off; off += (bytes + 255) & ~(size_t)255; return p; };
    int* ptr = (int*)carve((NN + 1) * sizeof(int));
    int* pos = (int*)carve((NN + 1) * sizeof(int));
    int* bsum = (int*)carve(256 * sizeof(int));
    int* offs = (int*)carve(256 * sizeof(int));
    int* srcadj = (int*)carve((size_t)(NEPU_MAX + NEPI_MAX) * sizeof(int));
    int* jit = (int*)carve((size_t)NEPU_MAX * sizeof(int));
    int* jpos1 = (int*)carve((size_t)NE * sizeof(int));
    float* dinv = (float*)carve(NN * sizeof(float));
    float4* Scur4 = (float4*)carve((size_t)NEPU_MAX * sizeof(float4));
    // contiguous zero-region: cnt | norm2 | wu | wi  (ONE bulk memset)
    size_t zbeg = off;
    int* cnt = (int*)carve((NN + 1) * sizeof(int));
    float2* norm2 = (float2*)carve((size_t)NEPU_MAX * sizeof(float2));
    float4* wu = (float4*)carve((size_t)NEPU_MAX * sizeof(float4));
    float4* wi = (float4*)carve((size_t)NEPI_MAX * sizeof(float4));
    size_t zlen = off - zbeg;
    unsigned short* egoUA = (unsigned short*)carve((size_t)NUM_USER * DIM * 2);
    unsigned short* egoUB = (unsigned short*)carve((size_t)NUM_USER * DIM * 2);
    unsigned* cmbIA = (unsigned*)carve((size_t)NUM_ITEM * DIM * 4);
    unsigned* cmbIB = (unsigned*)carve((size_t)NUM_ITEM * DIM * 4);

    hipMemsetAsync(ws + zbeg, 0, zlen, stream);

    k_setup<<<NB_SETUP, 256, 0, stream>>>(user, item, egoUA, cmbIA, allemb,
                                          row0, col0, cnt);
    k_scan1<<<NBLK_SCAN, SCAN_CHUNK, 0, stream>>>(cnt, dinv, ptr, bsum);
    k_scan2<<<1, 256, 0, stream>>>(bsum, offs);
    k_scan3<<<(NN + 1 + 255) / 256, 256, 0, stream>>>(ptr, offs, pos, cnt, srcadj);
    k_fillw0<<<(NE + 255) / 256, 256, 0, stream>>>(row0, col0, S_in, dinv, pos,
                                                   ptr, srcadj, jit, jpos1,
                                                   norm2, wu);

    unsigned short* egoU = egoUA;
    unsigned short* egoUn = egoUB;
    unsigned* cmbI = cmbIA;
    unsigned* cmbIn = cmbIB;
    for (int layer = 0; layer < 2; ++layer) {
        for (int it = 0; it < 2; ++it) {
            int flags = 0;
            if (it == 0) flags |= 8;                   // scatter wi (consumed at it=1)
            if (it == 1) flags |= 1;                   // layer end: allemb += acc
            if (it == 1 && layer == 0) flags |= 4;     // write next ego (+item T)
            int last = (layer == 1 && it == 1) ? 1 : 0;
            // non-layer-end: item x_new is never consumed -> user-only grid
            int nlim = (it == 1) ? NN : NUM_USER;
            k_conv_score<<<(nlim * 64 + 255) / 256, 256, 0, stream>>>(
                ptr, srcadj, (float*)wu, (float*)wi, (float*)Scur4, norm2, jit,
                egoU, cmbI, egoUn, cmbIn, allemb, flags, last, nlim);
        }
        unsigned short* t = egoU; egoU = egoUn; egoUn = t;
        unsigned* tc = cmbI; cmbI = cmbIn; cmbIn = tc;
    }
    k_sout<<<(NE + 255) / 256, 256, 0, stream>>>(Scur4, jpos1, Sfinal);
}